// Round 5
// baseline (12669.397 us; speedup 1.0000x reference)
//
#include <hip/hip_runtime.h>

#define B_ 2
#define C_ 8
#define F_ 256
#define W_ 512
#define H_ 8
#define FW_ (F_*W_)        // 131072
#define CFW_ (C_*FW_)      // 1048576 = one batch of (C,F,W)
// out is (B,16,F,W): batch stride 2*CFW_. x-half of batch b at out+b*2CFW_,
// h-half at out+b*2CFW_+CFW_.

// ---------------- init / final copy ----------------
__global__ __launch_bounds__(256)
void init_h(const float* __restrict__ x, float* __restrict__ out){
  int i = blockIdx.x*256 + threadIdx.x;              // 2M
  int b = i >> 20;
  int r = i & (CFW_-1);
  out[(size_t)b*2*CFW_ + CFW_ + r] = x[i];
}
__global__ __launch_bounds__(256)
void copy_x(const float* __restrict__ x, float* __restrict__ out){
  int i = blockIdx.x*256 + threadIdx.x;              // 2M
  int b = i >> 20;
  int r = i & (CFW_-1);
  out[(size_t)b*2*CFW_ + r] = x[i];
}

__global__ void put_val(float* o, float v){ o[0] = v; }

// ---------------- per-batch LayerNorm over f ----------------
// X,Y: (C,F,W). one thread per (c,w); grid 16, block 256
__global__ __launch_bounds__(256)
void ln_b(const float* __restrict__ X, float* __restrict__ Y,
          const float* __restrict__ g, const float* __restrict__ bta){
  int idx = blockIdx.x*256 + threadIdx.x;            // 4096
  int w = idx & (W_-1);
  int c = idx >> 9;
  const float* xb = X + (size_t)c*FW_ + w;
  float s = 0.f, q = 0.f;
  for (int f = 0; f < F_; ++f){
    float v = xb[(size_t)f*W_];
    s += v; q += v*v;
  }
  float mu = s * (1.f/256.f);
  float rs = rsqrtf(q * (1.f/256.f) - mu*mu + 1e-5f);
  float* yb = Y + (size_t)c*FW_ + w;
  for (int f = 0; f < F_; ++f){
    yb[(size_t)f*W_] = (xb[(size_t)f*W_] - mu)*rs*g[c*F_ + f] + bta[c*F_ + f];
  }
}

// ---------------- per-batch per-channel GEMM ----------------
// Y[c,g,w] (+)= sum_f A[c,g,f] * X[c,f,w];  one thread per output
template<int ACC>
__global__ __launch_bounds__(256)
void gemm_b(const float* __restrict__ A,
            const float* __restrict__ X, float* __restrict__ Y){
  int idx = blockIdx.x*256 + threadIdx.x;            // 1M
  int w = idx & (W_-1);
  int g = (idx >> 9) & (F_-1);
  int c = idx >> 17;
  const float* a  = A + ((size_t)c*F_ + g)*F_;
  const float* xb = X + (size_t)c*FW_ + w;
  float acc = 0.f;
  #pragma unroll 4
  for (int f = 0; f < F_; ++f) acc += a[f]*xb[(size_t)f*W_];
  float* y = Y + (size_t)c*FW_ + (size_t)g*W_ + w;
  if (ACC) *y += acc; else *y = acc;
}

// ---------------- per-batch channel-mix 1x3 conv along w ----------------
// O[co,f,w] = bias[co] + sum_{ci,kw} T[ci,f,w-1+kw]*K[co,ci,kw]; grid (2,256,8)
__global__ __launch_bounds__(256)
void conv1x3_b(const float* __restrict__ T, const float* __restrict__ K3,
               const float* __restrict__ bias, float* __restrict__ O){
  int w = blockIdx.x*256 + threadIdx.x;
  int f = blockIdx.y;
  int co = blockIdx.z;
  float acc = bias[co];
  #pragma unroll
  for (int ci = 0; ci < 8; ++ci){
    const float* row = T + ((size_t)ci*F_ + f)*W_;
    const float* kk = K3 + (co*8 + ci)*3;
    if (w > 0)      acc += kk[0]*row[w-1];
    acc += kk[1]*row[w];
    if (w < W_-1)   acc += kk[2]*row[w+1];
  }
  O[((size_t)co*F_ + f)*W_ + w] = acc;
}

// ---------------- per-batch interleaved RoPE in place ----------------
__global__ __launch_bounds__(256)
void rope_b(float* X){
  int idx = blockIdx.x*256 + threadIdx.x;            // 512K pairs
  int w = idx & (W_-1);
  int r = idx >> 9;
  int jf = r & 127;                                  // f-pair index, f0 = 2*jf
  int c = r >> 7;
  int j = jf & 15;                                   // freq index within head
  size_t base = ((size_t)c*F_ + jf*2)*W_ + w;
  float inv = exp2f(-(float)j * 0.83048202372184f);  // 10000^(-j/16)
  float ang = (float)w * inv;
  float sv, cv;
  sincosf(ang, &sv, &cv);
  float x0 = X[base], x1 = X[base + W_];
  X[base]      = x0*cv - x1*sv;
  X[base + W_] = x1*cv + x0*sv;
}

// ---------------- per-batch attention (one thread per query) ----------------
// q,k,v,a all (C,F,W) layout; head h occupies f in [h*32,(h+1)*32)
__global__ __launch_bounds__(256)
void attn_b(const float* __restrict__ q, const float* __restrict__ k,
            const float* __restrict__ v, float* __restrict__ a){
  int idx = blockIdx.x*256 + threadIdx.x;            // 32768
  int qi = idx & (W_-1);
  int h = (idx >> 9) & 7;
  int c = idx >> 12;
  size_t base = ((size_t)c*F_ + h*32)*W_;
  float qr[32];
  #pragma unroll
  for (int d = 0; d < 32; ++d)
    qr[d] = q[base + (size_t)d*W_ + qi] * 0.0625f;   // 1/sqrt(256)
  float mx = -1e30f, l = 0.f, acc[32] = {};
  for (int m = 0; m < W_; ++m){
    float s = 0.f;
    #pragma unroll
    for (int d = 0; d < 32; ++d) s += qr[d]*k[base + (size_t)d*W_ + m];
    float mn = fmaxf(mx, s);
    float corr = __expf(mx - mn);
    float p = __expf(s - mn);
    l = l*corr + p;
    #pragma unroll
    for (int d = 0; d < 32; ++d)
      acc[d] = acc[d]*corr + p*v[base + (size_t)d*W_ + m];
    mx = mn;
  }
  float inv = 1.f/l;
  #pragma unroll
  for (int d = 0; d < 32; ++d)
    a[base + (size_t)d*W_ + qi] = acc[d]*inv;
}

// ---------------- per-batch depthwise feature convs ----------------
// S = sq_relu(conv11(Z)) + conv7(Z); grid (2,256,8)
__global__ __launch_bounds__(256)
void dw_fuse_b(const float* __restrict__ Z,
               const float* __restrict__ k11, const float* __restrict__ b11,
               const float* __restrict__ k7,  const float* __restrict__ b7,
               float* __restrict__ S){
  int w = blockIdx.x*256 + threadIdx.x;
  int f = blockIdx.y;
  int c = blockIdx.z;
  const float* zb = Z + (size_t)c*FW_;
  float a = b11[c];
  #pragma unroll
  for (int i = 0; i < 11; ++i){
    int ff = f - 5 + i;
    if (ff >= 0 && ff < F_) a += k11[c*11 + i]*zb[(size_t)ff*W_ + w];
  }
  float bb = b7[c];
  #pragma unroll
  for (int i = 0; i < 7; ++i){
    int ff = f - 3 + i;
    if (ff >= 0 && ff < F_) bb += k7[c*7 + i]*zb[(size_t)ff*W_ + w];
  }
  float ra = a > 0.f ? a*a : 0.f;
  S[((size_t)c*F_ + f)*W_ + w] = ra + bb;
}

// H += conv7(T) + bias; grid (2,256,8)
__global__ __launch_bounds__(256)
void conv7_add_b(const float* __restrict__ T, const float* __restrict__ k7,
                 const float* __restrict__ b7, float* __restrict__ Hp){
  int w = blockIdx.x*256 + threadIdx.x;
  int f = blockIdx.y;
  int c = blockIdx.z;
  const float* tb = T + (size_t)c*FW_;
  float acc = b7[c];
  #pragma unroll
  for (int i = 0; i < 7; ++i){
    int ff = f - 3 + i;
    if (ff >= 0 && ff < F_) acc += k7[c*7 + i]*tb[(size_t)ff*W_ + w];
  }
  Hp[((size_t)c*F_ + f)*W_ + w] += acc;
}

// ---------------- per-batch tiny FF: H += w4 @ sq_relu(w3 @ Z) ----------------
__global__ __launch_bounds__(256)
void ff_b(const float* __restrict__ Z,
          const float* __restrict__ w3, const float* __restrict__ w4,
          float* __restrict__ Hp){
  int idx = blockIdx.x*256 + threadIdx.x;            // 4096
  int w = idx & (W_-1);
  int c = idx >> 9;
  const float* zb = Z + (size_t)c*FW_;
  float u[4] = {0,0,0,0};
  for (int f = 0; f < F_; ++f){
    float zv = zb[(size_t)f*W_ + w];
    #pragma unroll
    for (int e = 0; e < 4; ++e) u[e] += w3[(c*4 + e)*F_ + f]*zv;
  }
  #pragma unroll
  for (int e = 0; e < 4; ++e){ float r = u[e] > 0.f ? u[e] : 0.f; u[e] = r*r; }
  float* hb = Hp + (size_t)c*FW_;
  for (int f = 0; f < F_; ++f){
    const float* w4r = w4 + (c*F_ + f)*4;
    hb[(size_t)f*W_ + w] += w4r[0]*u[0] + w4r[1]*u[1] + w4r[2]*u[2] + w4r[3]*u[3];
  }
}

extern "C" void kernel_launch(void* const* d_in, const int* in_sizes, int n_in,
                              void* d_out, int out_size, void* d_ws, size_t ws_size,
                              hipStream_t stream){
  const float* x    = (const float*)d_in[0];
  const float* skip = (const float*)d_in[1];
  const float* Wq   = (const float*)d_in[2];
  const float* Kq   = (const float*)d_in[3];
  const float* bq   = (const float*)d_in[4];
  const float* Wk   = (const float*)d_in[5];
  const float* Kk   = (const float*)d_in[6];
  const float* bk   = (const float*)d_in[7];
  const float* Wv   = (const float*)d_in[8];
  const float* Kv   = (const float*)d_in[9];
  const float* bv   = (const float*)d_in[10];
  const float* Wo   = (const float*)d_in[11];
  const float* ng   = (const float*)d_in[12];
  const float* nb   = (const float*)d_in[13];
  const float* c1aw = (const float*)d_in[14];
  const float* c1ab = (const float*)d_in[15];
  const float* c1bw = (const float*)d_in[16];
  const float* c1bb = (const float*)d_in[17];
  const float* c2w  = (const float*)d_in[18];
  const float* c2b  = (const float*)d_in[19];
  const float* w3   = (const float*)d_in[20];
  const float* w4   = (const float*)d_in[21];

  float* out = (float*)d_out;

  // workspace: EXACTLY 3*CFW floats = 12,582,912 bytes (availability proven r3)
  float* ws = (float*)d_ws;
  float* tq = ws;                    // gemm temp t; later attn output a
  float* qb = ws + (size_t)CFW_;     // q
  float* kb = ws + (size_t)2*CFW_;   // k

  float code = 0.f;
  if (n_in != 22) code += 20000.f;
  if (out_size != 4194304) code += 80000.f;
  if (ws_size < (size_t)3*CFW_*4) code += 160000.f;

  dim3 gPix(2, F_, C_);

  init_h<<<8192, 256, 0, stream>>>(x, out);

  for (int b = 0; b < B_; ++b){
    const float* x_b    = x    + (size_t)b*CFW_;
    const float* skip_b = skip + (size_t)b*CFW_;
    float* zv_b = out + (size_t)b*2*CFW_;            // x-half scratch: z, then v
    float* h_b  = out + (size_t)b*2*CFW_ + CFW_;     // h accumulator

    auto do_attn = [&](int i, const float* srckv){
      const float* wq = Wq + (size_t)i*C_*F_*F_;
      const float* wk = Wk + (size_t)i*C_*F_*F_;
      const float* wv = Wv + (size_t)i*C_*F_*F_;
      const float* wo = Wo + (size_t)i*C_*F_*F_;
      gemm_b<0><<<4096, 256, 0, stream>>>(wq, zv_b, tq);
      conv1x3_b<<<gPix, 256, 0, stream>>>(tq, Kq + i*C_*C_*3, bq + i*C_, qb);
      rope_b<<<2048, 256, 0, stream>>>(qb);
      gemm_b<0><<<4096, 256, 0, stream>>>(wk, srckv, tq);
      conv1x3_b<<<gPix, 256, 0, stream>>>(tq, Kk + i*C_*C_*3, bk + i*C_, kb);
      rope_b<<<2048, 256, 0, stream>>>(kb);
      gemm_b<0><<<4096, 256, 0, stream>>>(wv, srckv, tq);
      conv1x3_b<<<gPix, 256, 0, stream>>>(tq, Kv + i*C_*C_*3, bv + i*C_, zv_b);
      attn_b<<<128, 256, 0, stream>>>(qb, kb, zv_b, tq);
      gemm_b<1><<<4096, 256, 0, stream>>>(wo, tq, h_b);
    };

    // h = x + att0(z,z) + att1(z,skip), z = LN0(x) (recomputed; v destroys zv)
    ln_b<<<16, 256, 0, stream>>>(x_b, zv_b, ng + 0*C_*F_, nb + 0*C_*F_);
    do_attn(0, zv_b);
    ln_b<<<16, 256, 0, stream>>>(x_b, zv_b, ng + 0*C_*F_, nb + 0*C_*F_);
    do_attn(1, skip_b);

    // conv block
    ln_b<<<16, 256, 0, stream>>>(h_b, zv_b, ng + 1*C_*F_, nb + 1*C_*F_);
    dw_fuse_b<<<gPix, 256, 0, stream>>>(zv_b, c1aw, c1ab, c1bw, c1bb, tq);
    ln_b<<<16, 256, 0, stream>>>(tq, qb, ng + 2*C_*F_, nb + 2*C_*F_);
    conv7_add_b<<<gPix, 256, 0, stream>>>(qb, c2w, c2b, h_b);

    // att2 (self on LN3(h))
    ln_b<<<16, 256, 0, stream>>>(h_b, zv_b, ng + 3*C_*F_, nb + 3*C_*F_);
    do_attn(2, zv_b);

    // att3 (LN4(h) vs skip)
    ln_b<<<16, 256, 0, stream>>>(h_b, zv_b, ng + 4*C_*F_, nb + 4*C_*F_);
    do_attn(3, skip_b);

    // FF
    ln_b<<<16, 256, 0, stream>>>(h_b, zv_b, ng + 5*C_*F_, nb + 5*C_*F_);
    ff_b<<<16, 256, 0, stream>>>(zv_b, w3, w4, h_b);
  }

  // restore the x-half of the output (both batches)
  copy_x<<<8192, 256, 0, stream>>>(x, out);

  if (code != 0.f) put_val<<<1, 1, 0, stream>>>(out, code);
}

// Round 6
// 2834.718 us; speedup vs baseline: 4.4694x; 4.4694x over previous
//
#include <hip/hip_runtime.h>

#define B_ 2
#define C_ 8
#define F_ 256
#define W_ 512
#define H_ 8
#define FW_ (F_*W_)        // 131072
#define CFW_ (C_*FW_)      // 1048576 = one batch of (C,F,W)
// out is (B,16,F,W): batch stride 2*CFW_. x-half of batch b at out+b*2CFW_,
// h-half at out+b*2CFW_+CFW_.

__device__ __forceinline__ float bfl(unsigned u){ return __uint_as_float(u<<16); }
__device__ __forceinline__ float bfh(unsigned u){ return __uint_as_float(u & 0xffff0000u); }
__device__ __forceinline__ unsigned short f2bf(float f){
  unsigned u = __float_as_uint(f);
  u += 0x7fffu + ((u>>16)&1u);
  return (unsigned short)(u>>16);
}

// ---------------- init / final copy ----------------
__global__ __launch_bounds__(256)
void init_h(const float* __restrict__ x, float* __restrict__ out){
  int i = blockIdx.x*256 + threadIdx.x;              // 2M
  int b = i >> 20;
  int r = i & (CFW_-1);
  out[(size_t)b*2*CFW_ + CFW_ + r] = x[i];
}
__global__ __launch_bounds__(256)
void copy_x(const float* __restrict__ x, float* __restrict__ out){
  int i = blockIdx.x*256 + threadIdx.x;              // 2M
  int b = i >> 20;
  int r = i & (CFW_-1);
  out[(size_t)b*2*CFW_ + r] = x[i];
}

__global__ void put_val(float* o, float v){ o[0] = v; }

// ---------------- per-batch LayerNorm over f (4 f-slices/column) ----------------
// grid (W/64=8, C=8), block 256 = 64 w-lanes x 4 f-slices
__global__ __launch_bounds__(256)
void ln4_b(const float* __restrict__ X, float* __restrict__ Y,
           const float* __restrict__ g, const float* __restrict__ bta){
  int wl = threadIdx.x & 63, fs = threadIdx.x >> 6;
  int w = blockIdx.x*64 + wl;
  int c = blockIdx.y;
  const float* xb = X + (size_t)c*FW_ + w;
  float sum = 0.f, sq = 0.f;
  for (int i = 0; i < 64; ++i){
    float v = xb[(size_t)(fs*64 + i)*W_];
    sum += v; sq += v*v;
  }
  __shared__ float Ssum[4][64], Ssq[4][64], Mu[64], Rs[64];
  Ssum[fs][wl] = sum; Ssq[fs][wl] = sq;
  __syncthreads();
  if (fs == 0){
    float s = Ssum[0][wl]+Ssum[1][wl]+Ssum[2][wl]+Ssum[3][wl];
    float q = Ssq[0][wl]+Ssq[1][wl]+Ssq[2][wl]+Ssq[3][wl];
    float mu = s * (1.f/256.f);
    float var = q * (1.f/256.f) - mu*mu;
    Mu[wl] = mu; Rs[wl] = rsqrtf(var + 1e-5f);
  }
  __syncthreads();
  float mu = Mu[wl], rs = Rs[wl];
  float* yb = Y + (size_t)c*FW_ + w;
  for (int i = 0; i < 64; ++i){
    int f = fs*64 + i;
    yb[(size_t)f*W_] = (xb[(size_t)f*W_] - mu)*rs*g[c*F_ + f] + bta[c*F_ + f];
  }
}

// ---------------- per-batch per-channel tiled GEMM ----------------
// Y[c,g,w] (+)= sum_f A[c,g,f] * X[c,f,w]
// grid (W/64=8, F/64=4, C=8), block 256, 64x64 tile, 4x4 microtile
template<int ACC>
__global__ __launch_bounds__(256)
void gemm64_b(const float* __restrict__ Wmat,
              const float* __restrict__ X, float* __restrict__ Y){
  int c = blockIdx.z;
  int m0 = blockIdx.y * 64;
  int n0 = blockIdx.x * 64;
  const float* A  = Wmat + (size_t)c*F_*F_;
  const float* Xb = X + (size_t)c*FW_;
  float*       Yb = Y + (size_t)c*FW_;

  __shared__ float As[16][64];
  __shared__ float Bs[16][68];

  int t = threadIdx.x;
  int tx = t & 15, ty = t >> 4;
  float acc[4][4] = {};

  for (int k0 = 0; k0 < F_; k0 += 16){
    {
      int m = t >> 2, kq = (t & 3) * 4;
      float4 av = *(const float4*)(A + (size_t)(m0 + m)*F_ + k0 + kq);
      As[kq+0][m] = av.x; As[kq+1][m] = av.y;
      As[kq+2][m] = av.z; As[kq+3][m] = av.w;
    }
    {
      int k = t >> 4, n4 = (t & 15) * 4;
      float4 bv = *(const float4*)(Xb + (size_t)(k0 + k)*W_ + n0 + n4);
      *(float4*)(&Bs[k][n4]) = bv;
    }
    __syncthreads();
    #pragma unroll
    for (int kk = 0; kk < 16; ++kk){
      float4 a4 = *(const float4*)(&As[kk][ty*4]);
      float4 b4 = *(const float4*)(&Bs[kk][tx*4]);
      float ar[4] = {a4.x, a4.y, a4.z, a4.w};
      float br[4] = {b4.x, b4.y, b4.z, b4.w};
      #pragma unroll
      for (int i = 0; i < 4; ++i)
        #pragma unroll
        for (int j = 0; j < 4; ++j)
          acc[i][j] += ar[i]*br[j];
    }
    __syncthreads();
  }
  #pragma unroll
  for (int i = 0; i < 4; ++i){
    int g = m0 + ty*4 + i;
    float* yrow = Yb + (size_t)g*W_ + n0 + tx*4;
    if (ACC){
      float4 old = *(float4*)yrow;
      old.x += acc[i][0]; old.y += acc[i][1];
      old.z += acc[i][2]; old.w += acc[i][3];
      *(float4*)yrow = old;
    } else {
      *(float4*)yrow = make_float4(acc[i][0], acc[i][1], acc[i][2], acc[i][3]);
    }
  }
}

// ---------------- per-batch channel-mix 1x3 conv (+ optional RoPE) ----------------
// Thread computes feature pair (f0=2*jf, f0+1) of output channel co at column w.
// grid 2048, block 256
template<int ROPE>
__global__ __launch_bounds__(256)
void conv_rope_b(const float* __restrict__ T, const float* __restrict__ K3,
                 const float* __restrict__ bias, float* __restrict__ O){
  int idx = blockIdx.x*256 + threadIdx.x;            // 524288
  int w = idx & (W_-1);
  int r = idx >> 9;
  int jf = r & 127;                                  // f-pair index, f0 = 2*jf
  int co = r >> 7;                                   // 0..7
  int f0 = jf*2;
  float a0 = bias[co], a1 = bias[co];
  #pragma unroll
  for (int ci = 0; ci < 8; ++ci){
    const float* row0 = T + ((size_t)ci*F_ + f0)*W_;
    const float* row1 = row0 + W_;
    const float* kk = K3 + (co*8 + ci)*3;
    float k0 = kk[0], k1 = kk[1], k2 = kk[2];
    if (w > 0){ a0 += k0*row0[w-1]; a1 += k0*row1[w-1]; }
    a0 += k1*row0[w]; a1 += k1*row1[w];
    if (w < W_-1){ a0 += k2*row0[w+1]; a1 += k2*row1[w+1]; }
  }
  size_t obase = ((size_t)co*F_ + f0)*W_ + w;
  if (ROPE){
    int j = jf & 15;                                 // freq index within head
    float inv = exp2f(-(float)j * 0.83048202372184f);  // 10000^(-j/16)
    float ang = (float)w * inv;
    float sv, cv;
    sincosf(ang, &sv, &cv);
    O[obase]      = a0*cv - a1*sv;
    O[obase + W_] = a1*cv + a0*sv;
  } else {
    O[obase]      = a0;
    O[obase + W_] = a1;
  }
}

// ---------------- per-batch attention, K/V staged in LDS as bf16 ----------------
// grid (C*H=64, 4 q-tiles), block 128: one query per thread, 8-key chunks.
__global__ __launch_bounds__(128)
void attn_lds(const float* __restrict__ q, const float* __restrict__ k,
              const float* __restrict__ v, float* __restrict__ a){
  __shared__ unsigned short Ks[32][W_];
  __shared__ unsigned short Vs[32][W_];
  int ch = blockIdx.x;
  int h = ch & 7, c = ch >> 3;
  size_t base = ((size_t)c*F_ + h*32)*W_;
  int t = threadIdx.x;
  unsigned short* ksf = &Ks[0][0];
  unsigned short* vsf = &Vs[0][0];
  for (int i = t; i < 32*W_; i += 128){
    ksf[i] = f2bf(k[base + i]);
    vsf[i] = f2bf(v[base + i]);
  }
  __syncthreads();
  int qi = blockIdx.y*128 + t;
  float qr[32];
  #pragma unroll
  for (int d = 0; d < 32; ++d)
    qr[d] = q[base + (size_t)d*W_ + qi] * 0.0625f;   // 1/sqrt(256)

  float acc[32] = {};
  float mrun = -1e30f, l = 0.f;

  for (int m0 = 0; m0 < W_; m0 += 8){
    float s[8] = {0,0,0,0,0,0,0,0};
    #pragma unroll
    for (int d = 0; d < 32; ++d){
      uint4 k4 = *(const uint4*)(&Ks[d][m0]);
      float qd = qr[d];
      s[0] += qd*bfl(k4.x); s[1] += qd*bfh(k4.x);
      s[2] += qd*bfl(k4.y); s[3] += qd*bfh(k4.y);
      s[4] += qd*bfl(k4.z); s[5] += qd*bfh(k4.z);
      s[6] += qd*bfl(k4.w); s[7] += qd*bfh(k4.w);
    }
    float cm = fmaxf(fmaxf(fmaxf(s[0],s[1]),fmaxf(s[2],s[3])),
                     fmaxf(fmaxf(s[4],s[5]),fmaxf(s[6],s[7])));
    float mnew = fmaxf(mrun, cm);
    float corr = __expf(mrun - mnew);
    float p[8];
    #pragma unroll
    for (int j = 0; j < 8; ++j) p[j] = __expf(s[j] - mnew);
    float ps = (p[0]+p[1])+(p[2]+p[3]);
    ps += (p[4]+p[5])+(p[6]+p[7]);
    l = l*corr + ps;
    #pragma unroll
    for (int d = 0; d < 32; ++d){
      uint4 v4 = *(const uint4*)(&Vs[d][m0]);
      float a0 = acc[d]*corr;
      a0 += p[0]*bfl(v4.x); a0 += p[1]*bfh(v4.x);
      a0 += p[2]*bfl(v4.y); a0 += p[3]*bfh(v4.y);
      a0 += p[4]*bfl(v4.z); a0 += p[5]*bfh(v4.z);
      a0 += p[6]*bfl(v4.w); a0 += p[7]*bfh(v4.w);
      acc[d] = a0;
    }
    mrun = mnew;
  }
  float inv = 1.f / l;
  #pragma unroll
  for (int d = 0; d < 32; ++d)
    a[base + (size_t)d*W_ + qi] = acc[d]*inv;
}

// ---------------- per-batch depthwise feature convs ----------------
__global__ __launch_bounds__(256)
void dw_fuse_b(const float* __restrict__ Z,
               const float* __restrict__ k11, const float* __restrict__ b11,
               const float* __restrict__ k7,  const float* __restrict__ b7,
               float* __restrict__ S){
  int w = blockIdx.x*256 + threadIdx.x;
  int f = blockIdx.y;
  int c = blockIdx.z;
  const float* zb = Z + (size_t)c*FW_;
  float a = b11[c];
  #pragma unroll
  for (int i = 0; i < 11; ++i){
    int ff = f - 5 + i;
    if (ff >= 0 && ff < F_) a += k11[c*11 + i]*zb[(size_t)ff*W_ + w];
  }
  float bb = b7[c];
  #pragma unroll
  for (int i = 0; i < 7; ++i){
    int ff = f - 3 + i;
    if (ff >= 0 && ff < F_) bb += k7[c*7 + i]*zb[(size_t)ff*W_ + w];
  }
  float ra = a > 0.f ? a*a : 0.f;
  S[((size_t)c*F_ + f)*W_ + w] = ra + bb;
}

__global__ __launch_bounds__(256)
void conv7_add_b(const float* __restrict__ T, const float* __restrict__ k7,
                 const float* __restrict__ b7, float* __restrict__ Hp){
  int w = blockIdx.x*256 + threadIdx.x;
  int f = blockIdx.y;
  int c = blockIdx.z;
  const float* tb = T + (size_t)c*FW_;
  float acc = b7[c];
  #pragma unroll
  for (int i = 0; i < 7; ++i){
    int ff = f - 3 + i;
    if (ff >= 0 && ff < F_) acc += k7[c*7 + i]*tb[(size_t)ff*W_ + w];
  }
  Hp[((size_t)c*F_ + f)*W_ + w] += acc;
}

// ---------------- per-batch tiny FF: H += w4 @ sq_relu(w3 @ Z) ----------------
__global__ __launch_bounds__(256)
void ff_b(const float* __restrict__ Z,
          const float* __restrict__ w3, const float* __restrict__ w4,
          float* __restrict__ Hp){
  int idx = blockIdx.x*256 + threadIdx.x;            // 4096
  int w = idx & (W_-1);
  int c = idx >> 9;
  const float* zb = Z + (size_t)c*FW_;
  float u[4] = {0,0,0,0};
  for (int f = 0; f < F_; ++f){
    float zv = zb[(size_t)f*W_ + w];
    #pragma unroll
    for (int e = 0; e < 4; ++e) u[e] += w3[(c*4 + e)*F_ + f]*zv;
  }
  #pragma unroll
  for (int e = 0; e < 4; ++e){ float r = u[e] > 0.f ? u[e] : 0.f; u[e] = r*r; }
  float* hb = Hp + (size_t)c*FW_;
  for (int f = 0; f < F_; ++f){
    const float* w4r = w4 + (c*F_ + f)*4;
    hb[(size_t)f*W_ + w] += w4r[0]*u[0] + w4r[1]*u[1] + w4r[2]*u[2] + w4r[3]*u[3];
  }
}

extern "C" void kernel_launch(void* const* d_in, const int* in_sizes, int n_in,
                              void* d_out, int out_size, void* d_ws, size_t ws_size,
                              hipStream_t stream){
  const float* x    = (const float*)d_in[0];
  const float* skip = (const float*)d_in[1];
  const float* Wq   = (const float*)d_in[2];
  const float* Kq   = (const float*)d_in[3];
  const float* bq   = (const float*)d_in[4];
  const float* Wk   = (const float*)d_in[5];
  const float* Kk   = (const float*)d_in[6];
  const float* bk   = (const float*)d_in[7];
  const float* Wv   = (const float*)d_in[8];
  const float* Kv   = (const float*)d_in[9];
  const float* bv   = (const float*)d_in[10];
  const float* Wo   = (const float*)d_in[11];
  const float* ng   = (const float*)d_in[12];
  const float* nb   = (const float*)d_in[13];
  const float* c1aw = (const float*)d_in[14];
  const float* c1ab = (const float*)d_in[15];
  const float* c1bw = (const float*)d_in[16];
  const float* c1bb = (const float*)d_in[17];
  const float* c2w  = (const float*)d_in[18];
  const float* c2b  = (const float*)d_in[19];
  const float* w3   = (const float*)d_in[20];
  const float* w4   = (const float*)d_in[21];

  float* out = (float*)d_out;

  // workspace: 3*CFW floats = 12,582,912 bytes
  float* ws = (float*)d_ws;
  float* tq = ws;                    // gemm temp t; later attn output a
  float* qb = ws + (size_t)CFW_;     // q
  float* kb = ws + (size_t)2*CFW_;   // k

  float code = 0.f;
  if (n_in != 22) code += 20000.f;
  if (out_size != 4194304) code += 80000.f;
  if (ws_size < (size_t)3*CFW_*4) code += 160000.f;

  dim3 gPix(2, F_, C_);
  dim3 gGemm(W_/64, F_/64, C_);
  dim3 gLn(W_/64, C_);
  dim3 gAttn(C_*H_, 4);

  init_h<<<8192, 256, 0, stream>>>(x, out);

  for (int b = 0; b < B_; ++b){
    const float* x_b    = x    + (size_t)b*CFW_;
    const float* skip_b = skip + (size_t)b*CFW_;
    float* zv_b = out + (size_t)b*2*CFW_;            // x-half scratch: z, then v
    float* h_b  = out + (size_t)b*2*CFW_ + CFW_;     // h accumulator

    auto do_attn = [&](int i, const float* srckv){
      const float* wq = Wq + (size_t)i*C_*F_*F_;
      const float* wk = Wk + (size_t)i*C_*F_*F_;
      const float* wv = Wv + (size_t)i*C_*F_*F_;
      const float* wo = Wo + (size_t)i*C_*F_*F_;
      gemm64_b<0><<<gGemm, 256, 0, stream>>>(wq, zv_b, tq);
      conv_rope_b<1><<<2048, 256, 0, stream>>>(tq, Kq + i*C_*C_*3, bq + i*C_, qb);
      gemm64_b<0><<<gGemm, 256, 0, stream>>>(wk, srckv, tq);
      conv_rope_b<1><<<2048, 256, 0, stream>>>(tq, Kk + i*C_*C_*3, bk + i*C_, kb);
      gemm64_b<0><<<gGemm, 256, 0, stream>>>(wv, srckv, tq);
      conv_rope_b<0><<<2048, 256, 0, stream>>>(tq, Kv + i*C_*C_*3, bv + i*C_, zv_b);
      attn_lds<<<gAttn, 128, 0, stream>>>(qb, kb, zv_b, tq);
      gemm64_b<1><<<gGemm, 256, 0, stream>>>(wo, tq, h_b);
    };

    // h = x + att0(z,z) + att1(z,skip), z = LN0(x) (recomputed; v destroys zv)
    ln4_b<<<gLn, 256, 0, stream>>>(x_b, zv_b, ng + 0*C_*F_, nb + 0*C_*F_);
    do_attn(0, zv_b);
    ln4_b<<<gLn, 256, 0, stream>>>(x_b, zv_b, ng + 0*C_*F_, nb + 0*C_*F_);
    do_attn(1, skip_b);

    // conv block
    ln4_b<<<gLn, 256, 0, stream>>>(h_b, zv_b, ng + 1*C_*F_, nb + 1*C_*F_);
    dw_fuse_b<<<gPix, 256, 0, stream>>>(zv_b, c1aw, c1ab, c1bw, c1bb, tq);
    ln4_b<<<gLn, 256, 0, stream>>>(tq, qb, ng + 2*C_*F_, nb + 2*C_*F_);
    conv7_add_b<<<gPix, 256, 0, stream>>>(qb, c2w, c2b, h_b);

    // att2 (self on LN3(h))
    ln4_b<<<gLn, 256, 0, stream>>>(h_b, zv_b, ng + 3*C_*F_, nb + 3*C_*F_);
    do_attn(2, zv_b);

    // att3 (LN4(h) vs skip)
    ln4_b<<<gLn, 256, 0, stream>>>(h_b, zv_b, ng + 4*C_*F_, nb + 4*C_*F_);
    do_attn(3, skip_b);

    // FF
    ln4_b<<<gLn, 256, 0, stream>>>(h_b, zv_b, ng + 5*C_*F_, nb + 5*C_*F_);
    ff_b<<<16, 256, 0, stream>>>(zv_b, w3, w4, h_b);
  }

  // restore the x-half of the output (both batches)
  copy_x<<<8192, 256, 0, stream>>>(x, out);

  if (code != 0.f) put_val<<<1, 1, 0, stream>>>(out, code);
}

// Round 7
// 1614.847 us; speedup vs baseline: 7.8456x; 1.7554x over previous
//
#include <hip/hip_runtime.h>

#define B_ 2
#define C_ 8
#define F_ 256
#define W_ 512
#define H_ 8
#define FW_ (F_*W_)        // 131072
#define CFW_ (C_*FW_)      // 1048576 = one batch of (C,F,W)
// out is (B,16,F,W): batch stride 2*CFW_. x-half of batch b at out+b*2CFW_,
// h-half at out+b*2CFW_+CFW_.

__device__ __forceinline__ float bfl(unsigned u){ return __uint_as_float(u<<16); }
__device__ __forceinline__ float bfh(unsigned u){ return __uint_as_float(u & 0xffff0000u); }
__device__ __forceinline__ unsigned short f2bf(float f){
  unsigned u = __float_as_uint(f);
  u += 0x7fffu + ((u>>16)&1u);
  return (unsigned short)(u>>16);
}

// ---------------- init / final copy ----------------
__global__ __launch_bounds__(256)
void init_h(const float* __restrict__ x, float* __restrict__ out){
  int i = blockIdx.x*256 + threadIdx.x;              // 2M
  int b = i >> 20;
  int r = i & (CFW_-1);
  out[(size_t)b*2*CFW_ + CFW_ + r] = x[i];
}
__global__ __launch_bounds__(256)
void copy_x(const float* __restrict__ x, float* __restrict__ out){
  int i = blockIdx.x*256 + threadIdx.x;              // 2M
  int b = i >> 20;
  int r = i & (CFW_-1);
  out[(size_t)b*2*CFW_ + r] = x[i];
}

__global__ void put_val(float* o, float v){ o[0] = v; }

// ---------------- per-batch LayerNorm over f (4 f-slices/column) ----------------
// grid (W/64=8, C=8), block 256 = 64 w-lanes x 4 f-slices
__global__ __launch_bounds__(256)
void ln4_b(const float* __restrict__ X, float* __restrict__ Y,
           const float* __restrict__ g, const float* __restrict__ bta){
  int wl = threadIdx.x & 63, fs = threadIdx.x >> 6;
  int w = blockIdx.x*64 + wl;
  int c = blockIdx.y;
  const float* xb = X + (size_t)c*FW_ + w;
  float sum = 0.f, sq = 0.f;
  for (int i = 0; i < 64; ++i){
    float v = xb[(size_t)(fs*64 + i)*W_];
    sum += v; sq += v*v;
  }
  __shared__ float Ssum[4][64], Ssq[4][64], Mu[64], Rs[64];
  Ssum[fs][wl] = sum; Ssq[fs][wl] = sq;
  __syncthreads();
  if (fs == 0){
    float s = Ssum[0][wl]+Ssum[1][wl]+Ssum[2][wl]+Ssum[3][wl];
    float q = Ssq[0][wl]+Ssq[1][wl]+Ssq[2][wl]+Ssq[3][wl];
    float mu = s * (1.f/256.f);
    float var = q * (1.f/256.f) - mu*mu;
    Mu[wl] = mu; Rs[wl] = rsqrtf(var + 1e-5f);
  }
  __syncthreads();
  float mu = Mu[wl], rs = Rs[wl];
  float* yb = Y + (size_t)c*FW_ + w;
  for (int i = 0; i < 64; ++i){
    int f = fs*64 + i;
    yb[(size_t)f*W_] = (xb[(size_t)f*W_] - mu)*rs*g[c*F_ + f] + bta[c*F_ + f];
  }
}

// ---------------- per-batch per-channel tiled GEMM ----------------
// Y[c,g,w] (+)= sum_f A[c,g,f] * X[c,f,w]
// grid (W/64=8, F/64=4, C=8), block 256, 64x64 tile, 4x4 microtile
template<int ACC>
__global__ __launch_bounds__(256)
void gemm64_b(const float* __restrict__ Wmat,
              const float* __restrict__ X, float* __restrict__ Y){
  int c = blockIdx.z;
  int m0 = blockIdx.y * 64;
  int n0 = blockIdx.x * 64;
  const float* A  = Wmat + (size_t)c*F_*F_;
  const float* Xb = X + (size_t)c*FW_;
  float*       Yb = Y + (size_t)c*FW_;

  __shared__ float As[16][64];
  __shared__ float Bs[16][68];

  int t = threadIdx.x;
  int tx = t & 15, ty = t >> 4;
  float acc[4][4] = {};

  for (int k0 = 0; k0 < F_; k0 += 16){
    {
      int m = t >> 2, kq = (t & 3) * 4;
      float4 av = *(const float4*)(A + (size_t)(m0 + m)*F_ + k0 + kq);
      As[kq+0][m] = av.x; As[kq+1][m] = av.y;
      As[kq+2][m] = av.z; As[kq+3][m] = av.w;
    }
    {
      int k = t >> 4, n4 = (t & 15) * 4;
      float4 bv = *(const float4*)(Xb + (size_t)(k0 + k)*W_ + n0 + n4);
      *(float4*)(&Bs[k][n4]) = bv;
    }
    __syncthreads();
    #pragma unroll
    for (int kk = 0; kk < 16; ++kk){
      float4 a4 = *(const float4*)(&As[kk][ty*4]);
      float4 b4 = *(const float4*)(&Bs[kk][tx*4]);
      float ar[4] = {a4.x, a4.y, a4.z, a4.w};
      float br[4] = {b4.x, b4.y, b4.z, b4.w};
      #pragma unroll
      for (int i = 0; i < 4; ++i)
        #pragma unroll
        for (int j = 0; j < 4; ++j)
          acc[i][j] += ar[i]*br[j];
    }
    __syncthreads();
  }
  #pragma unroll
  for (int i = 0; i < 4; ++i){
    int g = m0 + ty*4 + i;
    float* yrow = Yb + (size_t)g*W_ + n0 + tx*4;
    if (ACC){
      float4 old = *(float4*)yrow;
      old.x += acc[i][0]; old.y += acc[i][1];
      old.z += acc[i][2]; old.w += acc[i][3];
      *(float4*)yrow = old;
    } else {
      *(float4*)yrow = make_float4(acc[i][0], acc[i][1], acc[i][2], acc[i][3]);
    }
  }
}

// ---------------- per-batch channel-mix 1x3 conv (+ optional RoPE) ----------------
// Thread computes feature pair (f0=2*jf, f0+1) of output channel co at column w.
// grid 2048, block 256
template<int ROPE>
__global__ __launch_bounds__(256)
void conv_rope_b(const float* __restrict__ T, const float* __restrict__ K3,
                 const float* __restrict__ bias, float* __restrict__ O){
  int idx = blockIdx.x*256 + threadIdx.x;            // 524288
  int w = idx & (W_-1);
  int r = idx >> 9;
  int jf = r & 127;                                  // f-pair index, f0 = 2*jf
  int co = r >> 7;                                   // 0..7
  int f0 = jf*2;
  float a0 = bias[co], a1 = bias[co];
  #pragma unroll
  for (int ci = 0; ci < 8; ++ci){
    const float* row0 = T + ((size_t)ci*F_ + f0)*W_;
    const float* row1 = row0 + W_;
    const float* kk = K3 + (co*8 + ci)*3;
    float k0 = kk[0], k1 = kk[1], k2 = kk[2];
    if (w > 0){ a0 += k0*row0[w-1]; a1 += k0*row1[w-1]; }
    a0 += k1*row0[w]; a1 += k1*row1[w];
    if (w < W_-1){ a0 += k2*row0[w+1]; a1 += k2*row1[w+1]; }
  }
  size_t obase = ((size_t)co*F_ + f0)*W_ + w;
  if (ROPE){
    int j = jf & 15;                                 // freq index within head
    float inv = exp2f(-(float)j * 0.83048202372184f);  // 10000^(-j/16)
    float ang = (float)w * inv;
    float sv, cv;
    sincosf(ang, &sv, &cv);
    O[obase]      = a0*cv - a1*sv;
    O[obase + W_] = a1*cv + a0*sv;
  } else {
    O[obase]      = a0;
    O[obase + W_] = a1;
  }
}

// ---------------- per-batch attention, 4-way key-split ----------------
// grid (C*H=64, W/64=8), block 256 = 4 waves; wave s handles key slice
// [s*128, s*128+128) for 64 queries. K/V staged in LDS as bf16; partial
// (m,l,acc[32]) merged via LDS after a sync (reusing the K/V region).
__global__ __launch_bounds__(256)
void attn_split(const float* __restrict__ q, const float* __restrict__ k,
                const float* __restrict__ v, float* __restrict__ a){
  __shared__ __align__(16) unsigned char smem[65536];
  unsigned short* ksf = (unsigned short*)smem;            // [32][512] bf16
  unsigned short* vsf = (unsigned short*)(smem + 32768);  // [32][512] bf16
  int ch = blockIdx.x;
  int h = ch & 7, c = ch >> 3;
  size_t base = ((size_t)c*F_ + h*32)*W_;
  int t = threadIdx.x;

  // stage K,V (vectorized): 32*512 = 16384 elems, 256 thr * 4 = 16 iters
  for (int i4 = t*4; i4 < 32*W_; i4 += 256*4){
    float4 kv = *(const float4*)(k + base + i4);
    float4 vv = *(const float4*)(v + base + i4);
    ksf[i4+0] = f2bf(kv.x); ksf[i4+1] = f2bf(kv.y);
    ksf[i4+2] = f2bf(kv.z); ksf[i4+3] = f2bf(kv.w);
    vsf[i4+0] = f2bf(vv.x); vsf[i4+1] = f2bf(vv.y);
    vsf[i4+2] = f2bf(vv.z); vsf[i4+3] = f2bf(vv.w);
  }
  __syncthreads();

  int ql = t & 63;                 // query within tile (lane)
  int s  = t >> 6;                 // key slice (wave-uniform)
  int qi = blockIdx.y*64 + ql;
  float qr[32];
  #pragma unroll
  for (int d = 0; d < 32; ++d)
    qr[d] = q[base + (size_t)d*W_ + qi] * 0.0625f;   // 1/sqrt(256)

  float acc[32] = {};
  float mrun = -1e30f, l = 0.f;

  int m0beg = s*128;
  for (int m0 = m0beg; m0 < m0beg + 128; m0 += 8){
    float sc[8] = {0,0,0,0,0,0,0,0};
    #pragma unroll
    for (int d = 0; d < 32; ++d){
      uint4 k4 = *(const uint4*)(&ksf[d*W_ + m0]);
      float qd = qr[d];
      sc[0] += qd*bfl(k4.x); sc[1] += qd*bfh(k4.x);
      sc[2] += qd*bfl(k4.y); sc[3] += qd*bfh(k4.y);
      sc[4] += qd*bfl(k4.z); sc[5] += qd*bfh(k4.z);
      sc[6] += qd*bfl(k4.w); sc[7] += qd*bfh(k4.w);
    }
    float cm = fmaxf(fmaxf(fmaxf(sc[0],sc[1]),fmaxf(sc[2],sc[3])),
                     fmaxf(fmaxf(sc[4],sc[5]),fmaxf(sc[6],sc[7])));
    float mnew = fmaxf(mrun, cm);
    float corr = __expf(mrun - mnew);
    float p[8];
    #pragma unroll
    for (int j = 0; j < 8; ++j) p[j] = __expf(sc[j] - mnew);
    float ps = (p[0]+p[1])+(p[2]+p[3]);
    ps += (p[4]+p[5])+(p[6]+p[7]);
    l = l*corr + ps;
    #pragma unroll
    for (int d = 0; d < 32; ++d){
      uint4 v4 = *(const uint4*)(&vsf[d*W_ + m0]);
      float a0 = acc[d]*corr;
      a0 += p[0]*bfl(v4.x); a0 += p[1]*bfh(v4.x);
      a0 += p[2]*bfl(v4.y); a0 += p[3]*bfh(v4.y);
      a0 += p[4]*bfl(v4.z); a0 += p[5]*bfh(v4.z);
      a0 += p[6]*bfl(v4.w); a0 += p[7]*bfh(v4.w);
      acc[d] = a0;
    }
    mrun = mnew;
  }
  __syncthreads();                 // all waves done reading K/V

  // partials: part[(s*34 + j)*64 + q], j: 0=m, 1=l, 2..33=acc
  float* part = (float*)smem;      // 4*34*64 floats = 34,816 B < 64 KB
  part[(s*34 + 0)*64 + ql] = mrun;
  part[(s*34 + 1)*64 + ql] = l;
  #pragma unroll
  for (int d = 0; d < 32; ++d)
    part[(s*34 + 2 + d)*64 + ql] = acc[d];
  __syncthreads();

  if (t < 64){
    float M = part[0*64 + t];
    #pragma unroll
    for (int s2 = 1; s2 < 4; ++s2)
      M = fmaxf(M, part[(s2*34)*64 + t]);
    float L = 0.f, o[32] = {};
    #pragma unroll
    for (int s2 = 0; s2 < 4; ++s2){
      float wgt = __expf(part[(s2*34)*64 + t] - M);
      L += wgt * part[(s2*34 + 1)*64 + t];
      #pragma unroll
      for (int d = 0; d < 32; ++d)
        o[d] += wgt * part[(s2*34 + 2 + d)*64 + t];
    }
    float inv = 1.f / L;
    int qo = blockIdx.y*64 + t;
    #pragma unroll
    for (int d = 0; d < 32; ++d)
      a[base + (size_t)d*W_ + qo] = o[d]*inv;
  }
}

// ---------------- per-batch depthwise feature convs ----------------
__global__ __launch_bounds__(256)
void dw_fuse_b(const float* __restrict__ Z,
               const float* __restrict__ k11, const float* __restrict__ b11,
               const float* __restrict__ k7,  const float* __restrict__ b7,
               float* __restrict__ S){
  int w = blockIdx.x*256 + threadIdx.x;
  int f = blockIdx.y;
  int c = blockIdx.z;
  const float* zb = Z + (size_t)c*FW_;
  float a = b11[c];
  #pragma unroll
  for (int i = 0; i < 11; ++i){
    int ff = f - 5 + i;
    if (ff >= 0 && ff < F_) a += k11[c*11 + i]*zb[(size_t)ff*W_ + w];
  }
  float bb = b7[c];
  #pragma unroll
  for (int i = 0; i < 7; ++i){
    int ff = f - 3 + i;
    if (ff >= 0 && ff < F_) bb += k7[c*7 + i]*zb[(size_t)ff*W_ + w];
  }
  float ra = a > 0.f ? a*a : 0.f;
  S[((size_t)c*F_ + f)*W_ + w] = ra + bb;
}

__global__ __launch_bounds__(256)
void conv7_add_b(const float* __restrict__ T, const float* __restrict__ k7,
                 const float* __restrict__ b7, float* __restrict__ Hp){
  int w = blockIdx.x*256 + threadIdx.x;
  int f = blockIdx.y;
  int c = blockIdx.z;
  const float* tb = T + (size_t)c*FW_;
  float acc = b7[c];
  #pragma unroll
  for (int i = 0; i < 7; ++i){
    int ff = f - 3 + i;
    if (ff >= 0 && ff < F_) acc += k7[c*7 + i]*tb[(size_t)ff*W_ + w];
  }
  Hp[((size_t)c*F_ + f)*W_ + w] += acc;
}

// ---------------- per-batch tiny FF: H += w4 @ sq_relu(w3 @ Z) ----------------
__global__ __launch_bounds__(256)
void ff_b(const float* __restrict__ Z,
          const float* __restrict__ w3, const float* __restrict__ w4,
          float* __restrict__ Hp){
  int idx = blockIdx.x*256 + threadIdx.x;            // 4096
  int w = idx & (W_-1);
  int c = idx >> 9;
  const float* zb = Z + (size_t)c*FW_;
  float u[4] = {0,0,0,0};
  for (int f = 0; f < F_; ++f){
    float zv = zb[(size_t)f*W_ + w];
    #pragma unroll
    for (int e = 0; e < 4; ++e) u[e] += w3[(c*4 + e)*F_ + f]*zv;
  }
  #pragma unroll
  for (int e = 0; e < 4; ++e){ float r = u[e] > 0.f ? u[e] : 0.f; u[e] = r*r; }
  float* hb = Hp + (size_t)c*FW_;
  for (int f = 0; f < F_; ++f){
    const float* w4r = w4 + (c*F_ + f)*4;
    hb[(size_t)f*W_ + w] += w4r[0]*u[0] + w4r[1]*u[1] + w4r[2]*u[2] + w4r[3]*u[3];
  }
}

extern "C" void kernel_launch(void* const* d_in, const int* in_sizes, int n_in,
                              void* d_out, int out_size, void* d_ws, size_t ws_size,
                              hipStream_t stream){
  const float* x    = (const float*)d_in[0];
  const float* skip = (const float*)d_in[1];
  const float* Wq   = (const float*)d_in[2];
  const float* Kq   = (const float*)d_in[3];
  const float* bq   = (const float*)d_in[4];
  const float* Wk   = (const float*)d_in[5];
  const float* Kk   = (const float*)d_in[6];
  const float* bk   = (const float*)d_in[7];
  const float* Wv   = (const float*)d_in[8];
  const float* Kv   = (const float*)d_in[9];
  const float* bv   = (const float*)d_in[10];
  const float* Wo   = (const float*)d_in[11];
  const float* ng   = (const float*)d_in[12];
  const float* nb   = (const float*)d_in[13];
  const float* c1aw = (const float*)d_in[14];
  const float* c1ab = (const float*)d_in[15];
  const float* c1bw = (const float*)d_in[16];
  const float* c1bb = (const float*)d_in[17];
  const float* c2w  = (const float*)d_in[18];
  const float* c2b  = (const float*)d_in[19];
  const float* w3   = (const float*)d_in[20];
  const float* w4   = (const float*)d_in[21];

  float* out = (float*)d_out;

  // workspace: 3*CFW floats = 12,582,912 bytes
  float* ws = (float*)d_ws;
  float* tq = ws;                    // gemm temp t; later attn output a
  float* qb = ws + (size_t)CFW_;     // q
  float* kb = ws + (size_t)2*CFW_;   // k

  float code = 0.f;
  if (n_in != 22) code += 20000.f;
  if (out_size != 4194304) code += 80000.f;
  if (ws_size < (size_t)3*CFW_*4) code += 160000.f;

  dim3 gPix(2, F_, C_);
  dim3 gGemm(W_/64, F_/64, C_);
  dim3 gLn(W_/64, C_);
  dim3 gAttn(C_*H_, W_/64);

  init_h<<<8192, 256, 0, stream>>>(x, out);

  for (int b = 0; b < B_; ++b){
    const float* x_b    = x    + (size_t)b*CFW_;
    const float* skip_b = skip + (size_t)b*CFW_;
    float* zv_b = out + (size_t)b*2*CFW_;            // x-half scratch: z, then v
    float* h_b  = out + (size_t)b*2*CFW_ + CFW_;     // h accumulator

    auto do_attn = [&](int i, const float* srckv){
      const float* wq = Wq + (size_t)i*C_*F_*F_;
      const float* wk = Wk + (size_t)i*C_*F_*F_;
      const float* wv = Wv + (size_t)i*C_*F_*F_;
      const float* wo = Wo + (size_t)i*C_*F_*F_;
      gemm64_b<0><<<gGemm, 256, 0, stream>>>(wq, zv_b, tq);
      conv_rope_b<1><<<2048, 256, 0, stream>>>(tq, Kq + i*C_*C_*3, bq + i*C_, qb);
      gemm64_b<0><<<gGemm, 256, 0, stream>>>(wk, srckv, tq);
      conv_rope_b<1><<<2048, 256, 0, stream>>>(tq, Kk + i*C_*C_*3, bk + i*C_, kb);
      gemm64_b<0><<<gGemm, 256, 0, stream>>>(wv, srckv, tq);
      conv_rope_b<0><<<2048, 256, 0, stream>>>(tq, Kv + i*C_*C_*3, bv + i*C_, zv_b);
      attn_split<<<gAttn, 256, 0, stream>>>(qb, kb, zv_b, tq);
      gemm64_b<1><<<gGemm, 256, 0, stream>>>(wo, tq, h_b);
    };

    // h = x + att0(z,z) + att1(z,skip), z = LN0(x) (recomputed; v destroys zv)
    ln4_b<<<gLn, 256, 0, stream>>>(x_b, zv_b, ng + 0*C_*F_, nb + 0*C_*F_);
    do_attn(0, zv_b);
    ln4_b<<<gLn, 256, 0, stream>>>(x_b, zv_b, ng + 0*C_*F_, nb + 0*C_*F_);
    do_attn(1, skip_b);

    // conv block
    ln4_b<<<gLn, 256, 0, stream>>>(h_b, zv_b, ng + 1*C_*F_, nb + 1*C_*F_);
    dw_fuse_b<<<gPix, 256, 0, stream>>>(zv_b, c1aw, c1ab, c1bw, c1bb, tq);
    ln4_b<<<gLn, 256, 0, stream>>>(tq, qb, ng + 2*C_*F_, nb + 2*C_*F_);
    conv7_add_b<<<gPix, 256, 0, stream>>>(qb, c2w, c2b, h_b);

    // att2 (self on LN3(h))
    ln4_b<<<gLn, 256, 0, stream>>>(h_b, zv_b, ng + 3*C_*F_, nb + 3*C_*F_);
    do_attn(2, zv_b);

    // att3 (LN4(h) vs skip)
    ln4_b<<<gLn, 256, 0, stream>>>(h_b, zv_b, ng + 4*C_*F_, nb + 4*C_*F_);
    do_attn(3, skip_b);

    // FF
    ln4_b<<<gLn, 256, 0, stream>>>(h_b, zv_b, ng + 5*C_*F_, nb + 5*C_*F_);
    ff_b<<<16, 256, 0, stream>>>(zv_b, w3, w4, h_b);
  }

  // restore the x-half of the output (both batches)
  copy_x<<<8192, 256, 0, stream>>>(x, out);

  if (code != 0.f) put_val<<<1, 1, 0, stream>>>(out, code);
}

// Round 8
// 1150.128 us; speedup vs baseline: 11.0156x; 1.4041x over previous
//
#include <hip/hip_runtime.h>

#define B_ 2
#define C_ 8
#define F_ 256
#define W_ 512
#define H_ 8
#define FW_ (F_*W_)        // 131072
#define CFW_ (C_*FW_)      // 1048576 = one batch of (C,F,W)
// out is (B,16,F,W): batch stride 2*CFW_. x-half of batch b at out+b*2CFW_,
// h-half at out+b*2CFW_+CFW_.

__device__ __forceinline__ float bfl(unsigned u){ return __uint_as_float(u<<16); }
__device__ __forceinline__ float bfh(unsigned u){ return __uint_as_float(u & 0xffff0000u); }
__device__ __forceinline__ unsigned short f2bf(float f){
  unsigned u = __float_as_uint(f);
  u += 0x7fffu + ((u>>16)&1u);
  return (unsigned short)(u>>16);
}

typedef __attribute__((ext_vector_type(8))) short bf16x8;
typedef __attribute__((ext_vector_type(4))) float f32x4;

// ---------------- init / final copy ----------------
__global__ __launch_bounds__(256)
void init_h(const float* __restrict__ x, float* __restrict__ out){
  int i = blockIdx.x*256 + threadIdx.x;              // 2M
  int b = i >> 20;
  int r = i & (CFW_-1);
  out[(size_t)b*2*CFW_ + CFW_ + r] = x[i];
}
__global__ __launch_bounds__(256)
void copy_x(const float* __restrict__ x, float* __restrict__ out){
  int i = blockIdx.x*256 + threadIdx.x;              // 2M
  int b = i >> 20;
  int r = i & (CFW_-1);
  out[(size_t)b*2*CFW_ + r] = x[i];
}

__global__ void put_val(float* o, float v){ o[0] = v; }

// ---------------- per-batch LayerNorm over f (4 f-slices/column) ----------------
// grid (W/64=8, C=8), block 256 = 64 w-lanes x 4 f-slices
__global__ __launch_bounds__(256)
void ln4_b(const float* __restrict__ X, float* __restrict__ Y,
           const float* __restrict__ g, const float* __restrict__ bta){
  int wl = threadIdx.x & 63, fs = threadIdx.x >> 6;
  int w = blockIdx.x*64 + wl;
  int c = blockIdx.y;
  const float* xb = X + (size_t)c*FW_ + w;
  float sum = 0.f, sq = 0.f;
  for (int i = 0; i < 64; ++i){
    float v = xb[(size_t)(fs*64 + i)*W_];
    sum += v; sq += v*v;
  }
  __shared__ float Ssum[4][64], Ssq[4][64], Mu[64], Rs[64];
  Ssum[fs][wl] = sum; Ssq[fs][wl] = sq;
  __syncthreads();
  if (fs == 0){
    float s = Ssum[0][wl]+Ssum[1][wl]+Ssum[2][wl]+Ssum[3][wl];
    float q = Ssq[0][wl]+Ssq[1][wl]+Ssq[2][wl]+Ssq[3][wl];
    float mu = s * (1.f/256.f);
    float var = q * (1.f/256.f) - mu*mu;
    Mu[wl] = mu; Rs[wl] = rsqrtf(var + 1e-5f);
  }
  __syncthreads();
  float mu = Mu[wl], rs = Rs[wl];
  float* yb = Y + (size_t)c*FW_ + w;
  for (int i = 0; i < 64; ++i){
    int f = fs*64 + i;
    yb[(size_t)f*W_] = (xb[(size_t)f*W_] - mu)*rs*g[c*F_ + f] + bta[c*F_ + f];
  }
}

// ---------------- per-batch per-channel tiled GEMM ----------------
// Y[c,g,w] (+)= sum_f A[c,g,f] * X[c,f,w]
// grid (W/64=8, F/64=4, C=8), block 256, 64x64 tile, 4x4 microtile
template<int ACC>
__global__ __launch_bounds__(256)
void gemm64_b(const float* __restrict__ Wmat,
              const float* __restrict__ X, float* __restrict__ Y){
  int c = blockIdx.z;
  int m0 = blockIdx.y * 64;
  int n0 = blockIdx.x * 64;
  const float* A  = Wmat + (size_t)c*F_*F_;
  const float* Xb = X + (size_t)c*FW_;
  float*       Yb = Y + (size_t)c*FW_;

  __shared__ float As[16][64];
  __shared__ float Bs[16][68];

  int t = threadIdx.x;
  int tx = t & 15, ty = t >> 4;
  float acc[4][4] = {};

  for (int k0 = 0; k0 < F_; k0 += 16){
    {
      int m = t >> 2, kq = (t & 3) * 4;
      float4 av = *(const float4*)(A + (size_t)(m0 + m)*F_ + k0 + kq);
      As[kq+0][m] = av.x; As[kq+1][m] = av.y;
      As[kq+2][m] = av.z; As[kq+3][m] = av.w;
    }
    {
      int k = t >> 4, n4 = (t & 15) * 4;
      float4 bv = *(const float4*)(Xb + (size_t)(k0 + k)*W_ + n0 + n4);
      *(float4*)(&Bs[k][n4]) = bv;
    }
    __syncthreads();
    #pragma unroll
    for (int kk = 0; kk < 16; ++kk){
      float4 a4 = *(const float4*)(&As[kk][ty*4]);
      float4 b4 = *(const float4*)(&Bs[kk][tx*4]);
      float ar[4] = {a4.x, a4.y, a4.z, a4.w};
      float br[4] = {b4.x, b4.y, b4.z, b4.w};
      #pragma unroll
      for (int i = 0; i < 4; ++i)
        #pragma unroll
        for (int j = 0; j < 4; ++j)
          acc[i][j] += ar[i]*br[j];
    }
    __syncthreads();
  }
  #pragma unroll
  for (int i = 0; i < 4; ++i){
    int g = m0 + ty*4 + i;
    float* yrow = Yb + (size_t)g*W_ + n0 + tx*4;
    if (ACC){
      float4 old = *(float4*)yrow;
      old.x += acc[i][0]; old.y += acc[i][1];
      old.z += acc[i][2]; old.w += acc[i][3];
      *(float4*)yrow = old;
    } else {
      *(float4*)yrow = make_float4(acc[i][0], acc[i][1], acc[i][2], acc[i][3]);
    }
  }
}

// ---------------- per-batch channel-mix 1x3 conv (+ optional RoPE) ----------------
// Thread computes feature pair (f0=2*jf, f0+1) of output channel co at column w.
// grid 2048, block 256
template<int ROPE>
__global__ __launch_bounds__(256)
void conv_rope_b(const float* __restrict__ T, const float* __restrict__ K3,
                 const float* __restrict__ bias, float* __restrict__ O){
  int idx = blockIdx.x*256 + threadIdx.x;            // 524288
  int w = idx & (W_-1);
  int r = idx >> 9;
  int jf = r & 127;                                  // f-pair index, f0 = 2*jf
  int co = r >> 7;                                   // 0..7
  int f0 = jf*2;
  float a0 = bias[co], a1 = bias[co];
  #pragma unroll
  for (int ci = 0; ci < 8; ++ci){
    const float* row0 = T + ((size_t)ci*F_ + f0)*W_;
    const float* row1 = row0 + W_;
    const float* kk = K3 + (co*8 + ci)*3;
    float k0 = kk[0], k1 = kk[1], k2 = kk[2];
    if (w > 0){ a0 += k0*row0[w-1]; a1 += k0*row1[w-1]; }
    a0 += k1*row0[w]; a1 += k1*row1[w];
    if (w < W_-1){ a0 += k2*row0[w+1]; a1 += k2*row1[w+1]; }
  }
  size_t obase = ((size_t)co*F_ + f0)*W_ + w;
  if (ROPE){
    int j = jf & 15;                                 // freq index within head
    float inv = exp2f(-(float)j * 0.83048202372184f);  // 10000^(-j/16)
    float ang = (float)w * inv;
    float sv, cv;
    sincosf(ang, &sv, &cv);
    O[obase]      = a0*cv - a1*sv;
    O[obase + W_] = a1*cv + a0*sv;
  } else {
    O[obase]      = a0;
    O[obase + W_] = a1;
  }
}

// ---------------- per-batch MFMA attention ----------------
// grid (C*H=64, 4 q-tiles of 128), block 512 (8 waves, 16 queries each).
// LDS (dynamic, 109056 B): K_lds[512 m][40 d] bf16 (transposed, d-contiguous),
// V_lds[32 d][520 m] bf16 (m-contiguous), P per wave [16 q][136 m] bf16.
// S = (Q^T K)/16 via mfma_16x16x32 (K-dim = head_dim = 32, one MFMA/tile);
// online softmax per 128-key tile; PV via mfma with P bounced through LDS.
__global__ __launch_bounds__(512)
void attn_mfma(const float* __restrict__ q, const float* __restrict__ k,
               const float* __restrict__ v, float* __restrict__ a){
  extern __shared__ __align__(16) unsigned char smem_dyn[];
  unsigned short* ks = (unsigned short*)smem_dyn;   // [512][40]
  unsigned short* vs = ks + 512*40;                 // [32][520]
  unsigned short* ps = vs + 32*520;                 // [8][16][136]
  int ch = blockIdx.x;
  int h = ch & 7, c = ch >> 3;
  size_t base = ((size_t)c*F_ + h*32)*W_;
  int t = threadIdx.x;
  int lane = t & 63, wv = t >> 6;
  int g = lane >> 4, c16 = lane & 15;

  // Q fragment: A[row=q_local][k=d]: lane holds Q[d=8g+j][q0+c16] * scale
  int q0 = blockIdx.y*128 + wv*16;
  union { bf16x8 v8; unsigned short u[8]; } aq;
  #pragma unroll
  for (int j = 0; j < 8; ++j){
    float qv = q[base + (size_t)(8*g + j)*W_ + q0 + c16] * 0.0625f; // 1/sqrt(256)
    aq.u[j] = f2bf(qv);
  }

  // stage K transposed -> K_lds[m][d]
  for (int d = 0; d < 32; ++d)
    ks[t*40 + d] = f2bf(k[base + (size_t)d*W_ + t]);       // t = m (512)
  // stage V -> V_lds[d][m] (packed b32 writes, conflict-free)
  {
    int m2 = t & 255;
    #pragma unroll
    for (int it = 0; it < 16; ++it){
      int d = it*2 + (t >> 8);
      float2 vv = *(const float2*)(v + base + (size_t)d*W_ + 2*m2);
      unsigned pk = ((unsigned)f2bf(vv.y) << 16) | (unsigned)f2bf(vv.x);
      *(unsigned*)(vs + (size_t)d*520 + 2*m2) = pk;
    }
  }
  __syncthreads();

  unsigned short* pw = ps + (size_t)wv*16*136;

  float mrun[4] = {-3e38f,-3e38f,-3e38f,-3e38f};
  float lrun[4] = {0.f,0.f,0.f,0.f};
  const f32x4 zero4 = {0.f,0.f,0.f,0.f};
  f32x4 outacc[2] = {zero4, zero4};

  for (int kt = 0; kt < 4; ++kt){
    // scores: 8 sub-tiles of 16 keys; D[row=q(4g+reg)][col=key(m0+c16)]
    f32x4 sv[8];
    #pragma unroll
    for (int mi = 0; mi < 8; ++mi){
      int m0 = kt*128 + mi*16;
      bf16x8 kb8 = *(const bf16x8*)(ks + (size_t)(m0 + c16)*40 + 8*g);
      sv[mi] = __builtin_amdgcn_mfma_f32_16x16x32_bf16(aq.v8, kb8, zero4, 0, 0, 0);
    }
    // per-query tile max: in-lane over mi, cross-lane over the 16 key columns
    float pmax[4];
    #pragma unroll
    for (int r = 0; r < 4; ++r){
      float m = sv[0][r];
      #pragma unroll
      for (int mi = 1; mi < 8; ++mi) m = fmaxf(m, sv[mi][r]);
      pmax[r] = m;
    }
    #pragma unroll
    for (int mask = 1; mask <= 8; mask <<= 1){
      #pragma unroll
      for (int r = 0; r < 4; ++r)
        pmax[r] = fmaxf(pmax[r], __shfl_xor(pmax[r], mask));
    }
    float corr[4];
    #pragma unroll
    for (int r = 0; r < 4; ++r){
      float mn = fmaxf(mrun[r], pmax[r]);
      corr[r] = __expf(mrun[r] - mn);
      mrun[r] = mn;
      lrun[r] *= corr[r];
    }
    // P = exp(S - m), lane-partial l-sum; write P to wave-private LDS
    #pragma unroll
    for (int mi = 0; mi < 8; ++mi){
      #pragma unroll
      for (int r = 0; r < 4; ++r){
        float p = __expf(sv[mi][r] - mrun[r]);
        lrun[r] += p;
        pw[(size_t)(4*g + r)*136 + mi*16 + c16] = f2bf(p);
      }
    }
    f32x4 cv = {corr[0], corr[1], corr[2], corr[3]};
    outacc[0] *= cv;
    outacc[1] *= cv;
    // PV: A = P[q=c16][m-contig], B = V[k=m][n=d=c16]; accumulate over 4 m-chunks
    #pragma unroll
    for (int mc = 0; mc < 4; ++mc){
      bf16x8 pa  = *(const bf16x8*)(pw + (size_t)c16*136 + mc*32 + 8*g);
      bf16x8 vb0 = *(const bf16x8*)(vs + (size_t)c16*520      + kt*128 + mc*32 + 8*g);
      bf16x8 vb1 = *(const bf16x8*)(vs + (size_t)(16+c16)*520 + kt*128 + mc*32 + 8*g);
      outacc[0] = __builtin_amdgcn_mfma_f32_16x16x32_bf16(pa, vb0, outacc[0], 0, 0, 0);
      outacc[1] = __builtin_amdgcn_mfma_f32_16x16x32_bf16(pa, vb1, outacc[1], 0, 0, 0);
    }
  }
  // epilogue: reduce lane-partial l across the 16 key-column lanes
  float L[4];
  #pragma unroll
  for (int r = 0; r < 4; ++r){
    float s = lrun[r];
    #pragma unroll
    for (int mask = 1; mask <= 8; mask <<= 1) s += __shfl_xor(s, mask);
    L[r] = s;
  }
  #pragma unroll
  for (int dt = 0; dt < 2; ++dt){
    #pragma unroll
    for (int r = 0; r < 4; ++r)
      a[base + (size_t)(dt*16 + c16)*W_ + q0 + 4*g + r] = outacc[dt][r] / L[r];
  }
}

// ---------------- per-batch depthwise feature convs ----------------
__global__ __launch_bounds__(256)
void dw_fuse_b(const float* __restrict__ Z,
               const float* __restrict__ k11, const float* __restrict__ b11,
               const float* __restrict__ k7,  const float* __restrict__ b7,
               float* __restrict__ S){
  int w = blockIdx.x*256 + threadIdx.x;
  int f = blockIdx.y;
  int c = blockIdx.z;
  const float* zb = Z + (size_t)c*FW_;
  float a = b11[c];
  #pragma unroll
  for (int i = 0; i < 11; ++i){
    int ff = f - 5 + i;
    if (ff >= 0 && ff < F_) a += k11[c*11 + i]*zb[(size_t)ff*W_ + w];
  }
  float bb = b7[c];
  #pragma unroll
  for (int i = 0; i < 7; ++i){
    int ff = f - 3 + i;
    if (ff >= 0 && ff < F_) bb += k7[c*7 + i]*zb[(size_t)ff*W_ + w];
  }
  float ra = a > 0.f ? a*a : 0.f;
  S[((size_t)c*F_ + f)*W_ + w] = ra + bb;
}

__global__ __launch_bounds__(256)
void conv7_add_b(const float* __restrict__ T, const float* __restrict__ k7,
                 const float* __restrict__ b7, float* __restrict__ Hp){
  int w = blockIdx.x*256 + threadIdx.x;
  int f = blockIdx.y;
  int c = blockIdx.z;
  const float* tb = T + (size_t)c*FW_;
  float acc = b7[c];
  #pragma unroll
  for (int i = 0; i < 7; ++i){
    int ff = f - 3 + i;
    if (ff >= 0 && ff < F_) acc += k7[c*7 + i]*tb[(size_t)ff*W_ + w];
  }
  Hp[((size_t)c*F_ + f)*W_ + w] += acc;
}

// ---------------- per-batch tiny FF: H += w4 @ sq_relu(w3 @ Z) ----------------
__global__ __launch_bounds__(256)
void ff_b(const float* __restrict__ Z,
          const float* __restrict__ w3, const float* __restrict__ w4,
          float* __restrict__ Hp){
  int idx = blockIdx.x*256 + threadIdx.x;            // 4096
  int w = idx & (W_-1);
  int c = idx >> 9;
  const float* zb = Z + (size_t)c*FW_;
  float u[4] = {0,0,0,0};
  for (int f = 0; f < F_; ++f){
    float zv = zb[(size_t)f*W_ + w];
    #pragma unroll
    for (int e = 0; e < 4; ++e) u[e] += w3[(c*4 + e)*F_ + f]*zv;
  }
  #pragma unroll
  for (int e = 0; e < 4; ++e){ float r = u[e] > 0.f ? u[e] : 0.f; u[e] = r*r; }
  float* hb = Hp + (size_t)c*FW_;
  for (int f = 0; f < F_; ++f){
    const float* w4r = w4 + (c*F_ + f)*4;
    hb[(size_t)f*W_ + w] += w4r[0]*u[0] + w4r[1]*u[1] + w4r[2]*u[2] + w4r[3]*u[3];
  }
}

extern "C" void kernel_launch(void* const* d_in, const int* in_sizes, int n_in,
                              void* d_out, int out_size, void* d_ws, size_t ws_size,
                              hipStream_t stream){
  const float* x    = (const float*)d_in[0];
  const float* skip = (const float*)d_in[1];
  const float* Wq   = (const float*)d_in[2];
  const float* Kq   = (const float*)d_in[3];
  const float* bq   = (const float*)d_in[4];
  const float* Wk   = (const float*)d_in[5];
  const float* Kk   = (const float*)d_in[6];
  const float* bk   = (const float*)d_in[7];
  const float* Wv   = (const float*)d_in[8];
  const float* Kv   = (const float*)d_in[9];
  const float* bv   = (const float*)d_in[10];
  const float* Wo   = (const float*)d_in[11];
  const float* ng   = (const float*)d_in[12];
  const float* nb   = (const float*)d_in[13];
  const float* c1aw = (const float*)d_in[14];
  const float* c1ab = (const float*)d_in[15];
  const float* c1bw = (const float*)d_in[16];
  const float* c1bb = (const float*)d_in[17];
  const float* c2w  = (const float*)d_in[18];
  const float* c2b  = (const float*)d_in[19];
  const float* w3   = (const float*)d_in[20];
  const float* w4   = (const float*)d_in[21];

  float* out = (float*)d_out;

  // workspace: 3*CFW floats = 12,582,912 bytes
  float* ws = (float*)d_ws;
  float* tq = ws;                    // gemm temp t; later attn output a
  float* qb = ws + (size_t)CFW_;     // q
  float* kb = ws + (size_t)2*CFW_;   // k

  float code = 0.f;
  if (n_in != 22) code += 20000.f;
  if (out_size != 4194304) code += 80000.f;
  if (ws_size < (size_t)3*CFW_*4) code += 160000.f;

  dim3 gPix(2, F_, C_);
  dim3 gGemm(W_/64, F_/64, C_);
  dim3 gLn(W_/64, C_);
  dim3 gAttn(C_*H_, 4);
  const int attn_lds_bytes = (512*40 + 32*520 + 8*16*136) * 2;  // 109056

  init_h<<<8192, 256, 0, stream>>>(x, out);

  for (int b = 0; b < B_; ++b){
    const float* x_b    = x    + (size_t)b*CFW_;
    const float* skip_b = skip + (size_t)b*CFW_;
    float* zv_b = out + (size_t)b*2*CFW_;            // x-half scratch: z, then v
    float* h_b  = out + (size_t)b*2*CFW_ + CFW_;     // h accumulator

    auto do_attn = [&](int i, const float* srckv){
      const float* wq = Wq + (size_t)i*C_*F_*F_;
      const float* wk = Wk + (size_t)i*C_*F_*F_;
      const float* wv = Wv + (size_t)i*C_*F_*F_;
      const float* wo = Wo + (size_t)i*C_*F_*F_;
      gemm64_b<0><<<gGemm, 256, 0, stream>>>(wq, zv_b, tq);
      conv_rope_b<1><<<2048, 256, 0, stream>>>(tq, Kq + i*C_*C_*3, bq + i*C_, qb);
      gemm64_b<0><<<gGemm, 256, 0, stream>>>(wk, srckv, tq);
      conv_rope_b<1><<<2048, 256, 0, stream>>>(tq, Kk + i*C_*C_*3, bk + i*C_, kb);
      gemm64_b<0><<<gGemm, 256, 0, stream>>>(wv, srckv, tq);
      conv_rope_b<0><<<2048, 256, 0, stream>>>(tq, Kv + i*C_*C_*3, bv + i*C_, zv_b);
      attn_mfma<<<gAttn, 512, attn_lds_bytes, stream>>>(qb, kb, zv_b, tq);
      gemm64_b<1><<<gGemm, 256, 0, stream>>>(wo, tq, h_b);
    };

    // h = x + att0(z,z) + att1(z,skip), z = LN0(x) (recomputed; v destroys zv)
    ln4_b<<<gLn, 256, 0, stream>>>(x_b, zv_b, ng + 0*C_*F_, nb + 0*C_*F_);
    do_attn(0, zv_b);
    ln4_b<<<gLn, 256, 0, stream>>>(x_b, zv_b, ng + 0*C_*F_, nb + 0*C_*F_);
    do_attn(1, skip_b);

    // conv block
    ln4_b<<<gLn, 256, 0, stream>>>(h_b, zv_b, ng + 1*C_*F_, nb + 1*C_*F_);
    dw_fuse_b<<<gPix, 256, 0, stream>>>(zv_b, c1aw, c1ab, c1bw, c1bb, tq);
    ln4_b<<<gLn, 256, 0, stream>>>(tq, qb, ng + 2*C_*F_, nb + 2*C_*F_);
    conv7_add_b<<<gPix, 256, 0, stream>>>(qb, c2w, c2b, h_b);

    // att2 (self on LN3(h))
    ln4_b<<<gLn, 256, 0, stream>>>(h_b, zv_b, ng + 3*C_*F_, nb + 3*C_*F_);
    do_attn(2, zv_b);

    // att3 (LN4(h) vs skip)
    ln4_b<<<gLn, 256, 0, stream>>>(h_b, zv_b, ng + 4*C_*F_, nb + 4*C_*F_);
    do_attn(3, skip_b);

    // FF
    ln4_b<<<gLn, 256, 0, stream>>>(h_b, zv_b, ng + 5*C_*F_, nb + 5*C_*F_);
    ff_b<<<16, 256, 0, stream>>>(zv_b, w3, w4, h_b);
  }

  // restore the x-half of the output (both batches)
  copy_x<<<8192, 256, 0, stream>>>(x, out);

  if (code != 0.f) put_val<<<1, 1, 0, stream>>>(out, code);
}

// Round 9
// 826.628 us; speedup vs baseline: 15.3266x; 1.3913x over previous
//
#include <hip/hip_runtime.h>

#define B_ 2
#define C_ 8
#define F_ 256
#define W_ 512
#define H_ 8
#define FW_ (F_*W_)        // 131072
#define CFW_ (C_*FW_)      // 1048576 = one batch of (C,F,W)
// out is (B,16,F,W): batch stride 2*CFW_. x-half of batch b at out+b*2CFW_,
// h-half at out+b*2CFW_+CFW_.

__device__ __forceinline__ unsigned short f2bf(float f){
  unsigned u = __float_as_uint(f);
  u += 0x7fffu + ((u>>16)&1u);
  return (unsigned short)(u>>16);
}

typedef __attribute__((ext_vector_type(8))) short bf16x8;
typedef __attribute__((ext_vector_type(4))) float f32x4;

// ---------------- init / final copy ----------------
__global__ __launch_bounds__(256)
void init_h(const float* __restrict__ x, float* __restrict__ out){
  int i = blockIdx.x*256 + threadIdx.x;              // 2M
  int b = i >> 20;
  int r = i & (CFW_-1);
  out[(size_t)b*2*CFW_ + CFW_ + r] = x[i];
}
__global__ __launch_bounds__(256)
void copy_x(const float* __restrict__ x, float* __restrict__ out){
  int i = blockIdx.x*256 + threadIdx.x;              // 2M
  int b = i >> 20;
  int r = i & (CFW_-1);
  out[(size_t)b*2*CFW_ + r] = x[i];
}

__global__ void put_val(float* o, float v){ o[0] = v; }

// ---------------- per-batch LayerNorm over f (4 f-slices/column) ----------------
// grid (W/64=8, C=8), block 256 = 64 w-lanes x 4 f-slices
__global__ __launch_bounds__(256)
void ln4_b(const float* __restrict__ X, float* __restrict__ Y,
           const float* __restrict__ g, const float* __restrict__ bta){
  int wl = threadIdx.x & 63, fs = threadIdx.x >> 6;
  int w = blockIdx.x*64 + wl;
  int c = blockIdx.y;
  const float* xb = X + (size_t)c*FW_ + w;
  float sum = 0.f, sq = 0.f;
  for (int i = 0; i < 64; ++i){
    float v = xb[(size_t)(fs*64 + i)*W_];
    sum += v; sq += v*v;
  }
  __shared__ float Ssum[4][64], Ssq[4][64], Mu[64], Rs[64];
  Ssum[fs][wl] = sum; Ssq[fs][wl] = sq;
  __syncthreads();
  if (fs == 0){
    float s = Ssum[0][wl]+Ssum[1][wl]+Ssum[2][wl]+Ssum[3][wl];
    float q = Ssq[0][wl]+Ssq[1][wl]+Ssq[2][wl]+Ssq[3][wl];
    float mu = s * (1.f/256.f);
    float var = q * (1.f/256.f) - mu*mu;
    Mu[wl] = mu; Rs[wl] = rsqrtf(var + 1e-5f);
  }
  __syncthreads();
  float mu = Mu[wl], rs = Rs[wl];
  float* yb = Y + (size_t)c*FW_ + w;
  for (int i = 0; i < 64; ++i){
    int f = fs*64 + i;
    yb[(size_t)f*W_] = (xb[(size_t)f*W_] - mu)*rs*g[c*F_ + f] + bta[c*F_ + f];
  }
}

// ---------------- per-batch per-channel MFMA GEMM ----------------
// Y[c,g,w] (+)= sum_f A[c,g,f] * X[c,f,w]
// MFMA roles: A-operand = X (row m = w, k = f), B-operand = Wmat (k = f, n = g),
// D[row=w][col=g]. Tile 64 w x 32 g, block 256 (4 waves of 16 w), grid (8,8,8).
// Fragment layouts identical to the HW-validated attn_mfma kernel.
template<int ACC>
__global__ __launch_bounds__(256)
void gemm_mfma(const float* __restrict__ Wmat,
               const float* __restrict__ X, float* __restrict__ Y){
  int c = blockIdx.z;
  int w0 = blockIdx.x * 64;                  // M (w)
  int g0 = blockIdx.y * 32;                  // N (g)
  const float* Ax = X + (size_t)c*FW_;       // A[m=w][k=f] = X[f][w]
  const float* Bw = Wmat + (size_t)c*F_*F_;  // B[k=f][n=g] = W[g][f]
  float* Yb = Y + (size_t)c*FW_;
  int t = threadIdx.x, lane = t & 63, wv = t >> 6;
  int gq = lane >> 4, c16 = lane & 15;
  int wm = w0 + wv*16 + c16;                 // A-frag row (w)
  const f32x4 zero4 = {0.f,0.f,0.f,0.f};
  f32x4 acc[2] = {zero4, zero4};

  for (int k0 = 0; k0 < F_; k0 += 32){
    union { bf16x8 v8; unsigned short u[8]; } af;
    #pragma unroll
    for (int j = 0; j < 8; ++j)
      af.u[j] = f2bf(Ax[(size_t)(k0 + 8*gq + j)*W_ + wm]);
    #pragma unroll
    for (int nf = 0; nf < 2; ++nf){
      union { bf16x8 v8; unsigned short u[8]; } bf;
      const float* bp = Bw + (size_t)(g0 + nf*16 + c16)*F_ + k0 + 8*gq;
      #pragma unroll
      for (int j = 0; j < 8; ++j) bf.u[j] = f2bf(bp[j]);
      acc[nf] = __builtin_amdgcn_mfma_f32_16x16x32_bf16(af.v8, bf.v8, acc[nf], 0, 0, 0);
    }
  }
  int wout = w0 + wv*16 + 4*gq;              // D row block (4 consecutive w)
  #pragma unroll
  for (int nf = 0; nf < 2; ++nf){
    float* y = Yb + (size_t)(g0 + nf*16 + c16)*W_ + wout;
    float4 val = make_float4(acc[nf][0], acc[nf][1], acc[nf][2], acc[nf][3]);
    if (ACC){
      float4 o = *(float4*)y;
      val.x += o.x; val.y += o.y; val.z += o.z; val.w += o.w;
    }
    *(float4*)y = val;
  }
}

// ---------------- per-batch channel-mix 1x3 conv (+ optional RoPE), 4 w/thread ----
// thread -> (co, jf, wq): computes feature pair (2jf, 2jf+1) at w = 4wq..4wq+3.
// grid 512, block 256
template<int ROPE>
__global__ __launch_bounds__(256)
void conv_rope4(const float* __restrict__ T, const float* __restrict__ K3,
                const float* __restrict__ bias, float* __restrict__ O){
  int idx = blockIdx.x*256 + threadIdx.x;            // 131072
  int wq = idx & 127;
  int r  = idx >> 7;
  int jf = r & 127;                                  // f-pair index, f0 = 2*jf
  int co = r >> 7;                                   // 0..7
  int w0 = wq*4;
  int f0 = jf*2;
  float bs = bias[co];
  float a0[4] = {bs,bs,bs,bs}, a1[4] = {bs,bs,bs,bs};
  #pragma unroll
  for (int ci = 0; ci < 8; ++ci){
    const float* row0 = T + ((size_t)ci*F_ + f0)*W_;
    const float* row1 = row0 + W_;
    const float* kk = K3 + (co*8 + ci)*3;
    float k0 = kk[0], k1 = kk[1], k2 = kk[2];
    float4 m0 = *(const float4*)(row0 + w0);
    float4 m1 = *(const float4*)(row1 + w0);
    float l0 = (w0 > 0) ? row0[w0-1] : 0.f;
    float l1 = (w0 > 0) ? row1[w0-1] : 0.f;
    float e0 = (w0+4 < W_) ? row0[w0+4] : 0.f;
    float e1 = (w0+4 < W_) ? row1[w0+4] : 0.f;
    a0[0] += k0*l0   + k1*m0.x + k2*m0.y;
    a0[1] += k0*m0.x + k1*m0.y + k2*m0.z;
    a0[2] += k0*m0.y + k1*m0.z + k2*m0.w;
    a0[3] += k0*m0.z + k1*m0.w + k2*e0;
    a1[0] += k0*l1   + k1*m1.x + k2*m1.y;
    a1[1] += k0*m1.x + k1*m1.y + k2*m1.z;
    a1[2] += k0*m1.y + k1*m1.z + k2*m1.w;
    a1[3] += k0*m1.z + k1*m1.w + k2*e1;
  }
  size_t obase = ((size_t)co*F_ + f0)*W_ + w0;
  if (ROPE){
    int j = jf & 15;                                 // freq index within head
    float inv = exp2f(-(float)j * 0.83048202372184f);  // 10000^(-j/16)
    float sv, cv, ds, dc;
    sincosf((float)w0 * inv, &sv, &cv);
    sincosf(inv, &ds, &dc);
    float o0[4], o1[4];
    #pragma unroll
    for (int qd = 0; qd < 4; ++qd){
      o0[qd] = a0[qd]*cv - a1[qd]*sv;
      o1[qd] = a1[qd]*cv + a0[qd]*sv;
      float cn = cv*dc - sv*ds;                      // rotate angle by inv
      sv = sv*dc + cv*ds;
      cv = cn;
    }
    *(float4*)(O + obase)      = make_float4(o0[0], o0[1], o0[2], o0[3]);
    *(float4*)(O + obase + W_) = make_float4(o1[0], o1[1], o1[2], o1[3]);
  } else {
    *(float4*)(O + obase)      = make_float4(a0[0], a0[1], a0[2], a0[3]);
    *(float4*)(O + obase + W_) = make_float4(a1[0], a1[1], a1[2], a1[3]);
  }
}

// ---------------- per-batch MFMA attention ----------------
// grid (C*H=64, 4 q-tiles of 128), block 512 (8 waves, 16 queries each).
__global__ __launch_bounds__(512)
void attn_mfma(const float* __restrict__ q, const float* __restrict__ k,
               const float* __restrict__ v, float* __restrict__ a){
  extern __shared__ __align__(16) unsigned char smem_dyn[];
  unsigned short* ks = (unsigned short*)smem_dyn;   // [512][40]
  unsigned short* vs = ks + 512*40;                 // [32][520]
  unsigned short* ps = vs + 32*520;                 // [8][16][136]
  int ch = blockIdx.x;
  int h = ch & 7, c = ch >> 3;
  size_t base = ((size_t)c*F_ + h*32)*W_;
  int t = threadIdx.x;
  int lane = t & 63, wv = t >> 6;
  int g = lane >> 4, c16 = lane & 15;

  int q0 = blockIdx.y*128 + wv*16;
  union { bf16x8 v8; unsigned short u[8]; } aq;
  #pragma unroll
  for (int j = 0; j < 8; ++j){
    float qv = q[base + (size_t)(8*g + j)*W_ + q0 + c16] * 0.0625f; // 1/sqrt(256)
    aq.u[j] = f2bf(qv);
  }

  for (int d = 0; d < 32; ++d)
    ks[t*40 + d] = f2bf(k[base + (size_t)d*W_ + t]);       // t = m (512)
  {
    int m2 = t & 255;
    #pragma unroll
    for (int it = 0; it < 16; ++it){
      int d = it*2 + (t >> 8);
      float2 vv = *(const float2*)(v + base + (size_t)d*W_ + 2*m2);
      unsigned pk = ((unsigned)f2bf(vv.y) << 16) | (unsigned)f2bf(vv.x);
      *(unsigned*)(vs + (size_t)d*520 + 2*m2) = pk;
    }
  }
  __syncthreads();

  unsigned short* pw = ps + (size_t)wv*16*136;

  float mrun[4] = {-3e38f,-3e38f,-3e38f,-3e38f};
  float lrun[4] = {0.f,0.f,0.f,0.f};
  const f32x4 zero4 = {0.f,0.f,0.f,0.f};
  f32x4 outacc[2] = {zero4, zero4};

  for (int kt = 0; kt < 4; ++kt){
    f32x4 sv[8];
    #pragma unroll
    for (int mi = 0; mi < 8; ++mi){
      int m0 = kt*128 + mi*16;
      bf16x8 kb8 = *(const bf16x8*)(ks + (size_t)(m0 + c16)*40 + 8*g);
      sv[mi] = __builtin_amdgcn_mfma_f32_16x16x32_bf16(aq.v8, kb8, zero4, 0, 0, 0);
    }
    float pmax[4];
    #pragma unroll
    for (int r = 0; r < 4; ++r){
      float m = sv[0][r];
      #pragma unroll
      for (int mi = 1; mi < 8; ++mi) m = fmaxf(m, sv[mi][r]);
      pmax[r] = m;
    }
    #pragma unroll
    for (int mask = 1; mask <= 8; mask <<= 1){
      #pragma unroll
      for (int r = 0; r < 4; ++r)
        pmax[r] = fmaxf(pmax[r], __shfl_xor(pmax[r], mask));
    }
    float corr[4];
    #pragma unroll
    for (int r = 0; r < 4; ++r){
      float mn = fmaxf(mrun[r], pmax[r]);
      corr[r] = __expf(mrun[r] - mn);
      mrun[r] = mn;
      lrun[r] *= corr[r];
    }
    #pragma unroll
    for (int mi = 0; mi < 8; ++mi){
      #pragma unroll
      for (int r = 0; r < 4; ++r){
        float p = __expf(sv[mi][r] - mrun[r]);
        lrun[r] += p;
        pw[(size_t)(4*g + r)*136 + mi*16 + c16] = f2bf(p);
      }
    }
    f32x4 cv = {corr[0], corr[1], corr[2], corr[3]};
    outacc[0] *= cv;
    outacc[1] *= cv;
    #pragma unroll
    for (int mc = 0; mc < 4; ++mc){
      bf16x8 pa  = *(const bf16x8*)(pw + (size_t)c16*136 + mc*32 + 8*g);
      bf16x8 vb0 = *(const bf16x8*)(vs + (size_t)c16*520      + kt*128 + mc*32 + 8*g);
      bf16x8 vb1 = *(const bf16x8*)(vs + (size_t)(16+c16)*520 + kt*128 + mc*32 + 8*g);
      outacc[0] = __builtin_amdgcn_mfma_f32_16x16x32_bf16(pa, vb0, outacc[0], 0, 0, 0);
      outacc[1] = __builtin_amdgcn_mfma_f32_16x16x32_bf16(pa, vb1, outacc[1], 0, 0, 0);
    }
  }
  float L[4];
  #pragma unroll
  for (int r = 0; r < 4; ++r){
    float s = lrun[r];
    #pragma unroll
    for (int mask = 1; mask <= 8; mask <<= 1) s += __shfl_xor(s, mask);
    L[r] = s;
  }
  #pragma unroll
  for (int dt = 0; dt < 2; ++dt){
    #pragma unroll
    for (int r = 0; r < 4; ++r)
      a[base + (size_t)(dt*16 + c16)*W_ + q0 + 4*g + r] = outacc[dt][r] / L[r];
  }
}

// ---------------- per-batch depthwise feature convs ----------------
__global__ __launch_bounds__(256)
void dw_fuse_b(const float* __restrict__ Z,
               const float* __restrict__ k11, const float* __restrict__ b11,
               const float* __restrict__ k7,  const float* __restrict__ b7,
               float* __restrict__ S){
  int w = blockIdx.x*256 + threadIdx.x;
  int f = blockIdx.y;
  int c = blockIdx.z;
  const float* zb = Z + (size_t)c*FW_;
  float a = b11[c];
  #pragma unroll
  for (int i = 0; i < 11; ++i){
    int ff = f - 5 + i;
    if (ff >= 0 && ff < F_) a += k11[c*11 + i]*zb[(size_t)ff*W_ + w];
  }
  float bb = b7[c];
  #pragma unroll
  for (int i = 0; i < 7; ++i){
    int ff = f - 3 + i;
    if (ff >= 0 && ff < F_) bb += k7[c*7 + i]*zb[(size_t)ff*W_ + w];
  }
  float ra = a > 0.f ? a*a : 0.f;
  S[((size_t)c*F_ + f)*W_ + w] = ra + bb;
}

__global__ __launch_bounds__(256)
void conv7_add_b(const float* __restrict__ T, const float* __restrict__ k7,
                 const float* __restrict__ b7, float* __restrict__ Hp){
  int w = blockIdx.x*256 + threadIdx.x;
  int f = blockIdx.y;
  int c = blockIdx.z;
  const float* tb = T + (size_t)c*FW_;
  float acc = b7[c];
  #pragma unroll
  for (int i = 0; i < 7; ++i){
    int ff = f - 3 + i;
    if (ff >= 0 && ff < F_) acc += k7[c*7 + i]*tb[(size_t)ff*W_ + w];
  }
  Hp[((size_t)c*F_ + f)*W_ + w] += acc;
}

// ---------------- per-batch tiny FF (parallel): H += w4 @ sq_relu(w3 @ Z) ------
// grid (W/64=8, C=8), block 256 = 64 w-lanes x 4 f-slices; 4 KB LDS reduce
__global__ __launch_bounds__(256)
void ff_b2(const float* __restrict__ Z,
           const float* __restrict__ w3, const float* __restrict__ w4,
           float* __restrict__ Hp){
  int wl = threadIdx.x & 63, fs = threadIdx.x >> 6;
  int w = blockIdx.x*64 + wl;
  int c = blockIdx.y;
  const float* zb = Z + (size_t)c*FW_ + w;
  float u[4] = {0.f,0.f,0.f,0.f};
  for (int i = 0; i < 64; ++i){
    int f = fs*64 + i;
    float zv = zb[(size_t)f*W_];
    #pragma unroll
    for (int e = 0; e < 4; ++e) u[e] += w3[(c*4 + e)*F_ + f]*zv;
  }
  __shared__ float Us[4][4][64];
  #pragma unroll
  for (int e = 0; e < 4; ++e) Us[fs][e][wl] = u[e];
  __syncthreads();
  float uf[4];
  #pragma unroll
  for (int e = 0; e < 4; ++e){
    float s = Us[0][e][wl] + Us[1][e][wl] + Us[2][e][wl] + Us[3][e][wl];
    float rr = s > 0.f ? s : 0.f;
    uf[e] = rr*rr;
  }
  float* hb = Hp + (size_t)c*FW_ + w;
  for (int i = 0; i < 64; ++i){
    int f = fs*64 + i;
    const float* w4r = w4 + (c*F_ + f)*4;
    hb[(size_t)f*W_] += w4r[0]*uf[0] + w4r[1]*uf[1] + w4r[2]*uf[2] + w4r[3]*uf[3];
  }
}

extern "C" void kernel_launch(void* const* d_in, const int* in_sizes, int n_in,
                              void* d_out, int out_size, void* d_ws, size_t ws_size,
                              hipStream_t stream){
  const float* x    = (const float*)d_in[0];
  const float* skip = (const float*)d_in[1];
  const float* Wq   = (const float*)d_in[2];
  const float* Kq   = (const float*)d_in[3];
  const float* bq   = (const float*)d_in[4];
  const float* Wk   = (const float*)d_in[5];
  const float* Kk   = (const float*)d_in[6];
  const float* bk   = (const float*)d_in[7];
  const float* Wv   = (const float*)d_in[8];
  const float* Kv   = (const float*)d_in[9];
  const float* bv   = (const float*)d_in[10];
  const float* Wo   = (const float*)d_in[11];
  const float* ng   = (const float*)d_in[12];
  const float* nb   = (const float*)d_in[13];
  const float* c1aw = (const float*)d_in[14];
  const float* c1ab = (const float*)d_in[15];
  const float* c1bw = (const float*)d_in[16];
  const float* c1bb = (const float*)d_in[17];
  const float* c2w  = (const float*)d_in[18];
  const float* c2b  = (const float*)d_in[19];
  const float* w3   = (const float*)d_in[20];
  const float* w4   = (const float*)d_in[21];

  float* out = (float*)d_out;

  // workspace: 3*CFW floats = 12,582,912 bytes
  float* ws = (float*)d_ws;
  float* tq = ws;                    // gemm temp t; later attn output a
  float* qb = ws + (size_t)CFW_;     // q
  float* kb = ws + (size_t)2*CFW_;   // k

  float code = 0.f;
  if (n_in != 22) code += 20000.f;
  if (out_size != 4194304) code += 80000.f;
  if (ws_size < (size_t)3*CFW_*4) code += 160000.f;

  dim3 gPix(2, F_, C_);
  dim3 gGemm(W_/64, F_/32, C_);      // 8 x 8 x 8 = 512 blocks
  dim3 gLn(W_/64, C_);
  dim3 gAttn(C_*H_, 4);
  const int attn_lds_bytes = (512*40 + 32*520 + 8*16*136) * 2;  // 109056

  init_h<<<8192, 256, 0, stream>>>(x, out);

  for (int b = 0; b < B_; ++b){
    const float* x_b    = x    + (size_t)b*CFW_;
    const float* skip_b = skip + (size_t)b*CFW_;
    float* zv_b = out + (size_t)b*2*CFW_;            // x-half scratch: z, then v
    float* h_b  = out + (size_t)b*2*CFW_ + CFW_;     // h accumulator

    auto do_attn = [&](int i, const float* srckv){
      const float* wq = Wq + (size_t)i*C_*F_*F_;
      const float* wk = Wk + (size_t)i*C_*F_*F_;
      const float* wv = Wv + (size_t)i*C_*F_*F_;
      const float* wo = Wo + (size_t)i*C_*F_*F_;
      gemm_mfma<0><<<gGemm, 256, 0, stream>>>(wq, zv_b, tq);
      conv_rope4<1><<<512, 256, 0, stream>>>(tq, Kq + i*C_*C_*3, bq + i*C_, qb);
      gemm_mfma<0><<<gGemm, 256, 0, stream>>>(wk, srckv, tq);
      conv_rope4<1><<<512, 256, 0, stream>>>(tq, Kk + i*C_*C_*3, bk + i*C_, kb);
      gemm_mfma<0><<<gGemm, 256, 0, stream>>>(wv, srckv, tq);
      conv_rope4<0><<<512, 256, 0, stream>>>(tq, Kv + i*C_*C_*3, bv + i*C_, zv_b);
      attn_mfma<<<gAttn, 512, attn_lds_bytes, stream>>>(qb, kb, zv_b, tq);
      gemm_mfma<1><<<gGemm, 256, 0, stream>>>(wo, tq, h_b);
    };

    // h = x + att0(z,z) + att1(z,skip), z = LN0(x) (recomputed; v destroys zv)
    ln4_b<<<gLn, 256, 0, stream>>>(x_b, zv_b, ng + 0*C_*F_, nb + 0*C_*F_);
    do_attn(0, zv_b);
    ln4_b<<<gLn, 256, 0, stream>>>(x_b, zv_b, ng + 0*C_*F_, nb + 0*C_*F_);
    do_attn(1, skip_b);

    // conv block
    ln4_b<<<gLn, 256, 0, stream>>>(h_b, zv_b, ng + 1*C_*F_, nb + 1*C_*F_);
    dw_fuse_b<<<gPix, 256, 0, stream>>>(zv_b, c1aw, c1ab, c1bw, c1bb, tq);
    ln4_b<<<gLn, 256, 0, stream>>>(tq, qb, ng + 2*C_*F_, nb + 2*C_*F_);
    conv7_add_b<<<gPix, 256, 0, stream>>>(qb, c2w, c2b, h_b);

    // att2 (self on LN3(h))
    ln4_b<<<gLn, 256, 0, stream>>>(h_b, zv_b, ng + 3*C_*F_, nb + 3*C_*F_);
    do_attn(2, zv_b);

    // att3 (LN4(h) vs skip)
    ln4_b<<<gLn, 256, 0, stream>>>(h_b, zv_b, ng + 4*C_*F_, nb + 4*C_*F_);
    do_attn(3, skip_b);

    // FF
    ln4_b<<<gLn, 256, 0, stream>>>(h_b, zv_b, ng + 5*C_*F_, nb + 5*C_*F_);
    ff_b2<<<gLn, 256, 0, stream>>>(zv_b, w3, w4, h_b);
  }

  // restore the x-half of the output (both batches)
  copy_x<<<8192, 256, 0, stream>>>(x, out);

  if (code != 0.f) put_val<<<1, 1, 0, stream>>>(out, code);
}

// Round 10
// 613.439 us; speedup vs baseline: 20.6531x; 1.3475x over previous
//
#include <hip/hip_runtime.h>

#define B_ 2
#define C_ 8
#define F_ 256
#define W_ 512
#define H_ 8
#define FW_ (F_*W_)        // 131072
#define CFW_ (C_*FW_)      // 1048576 = one batch of (C,F,W)
#define OBS_ (2*CFW_)      // out batch stride (B,16,F,W)

__device__ __forceinline__ unsigned short f2bf(float f){
  unsigned u = __float_as_uint(f);
  u += 0x7fffu + ((u>>16)&1u);
  return (unsigned short)(u>>16);
}

typedef __attribute__((ext_vector_type(8))) short bf16x8;
typedef __attribute__((ext_vector_type(4))) float f32x4;

// ---------------- init: both halves of out = x ----------------
__global__ __launch_bounds__(256)
void init_out(const float* __restrict__ x, float* __restrict__ out){
  int i = blockIdx.x*256 + threadIdx.x;              // 2M
  int b = i >> 20;
  int r = i & (CFW_-1);
  float v = x[i];
  out[(size_t)b*OBS_ + r] = v;
  out[(size_t)b*OBS_ + CFW_ + r] = v;
}

__global__ void put_val(float* o, float v){ o[0] = v; }

// ---------------- LayerNorm over f (4 f-slices/column), batch in grid.z ------
// grid (W/64=8, C=8, B=2), block 256
__global__ __launch_bounds__(256)
void ln4_b(const float* __restrict__ X, long xbs, float* __restrict__ Y, long ybs,
           const float* __restrict__ g, const float* __restrict__ bta){
  int wl = threadIdx.x & 63, fs = threadIdx.x >> 6;
  int w = blockIdx.x*64 + wl;
  int c = blockIdx.y;
  int b = blockIdx.z;
  const float* xb = X + (size_t)b*xbs + (size_t)c*FW_ + w;
  float sum = 0.f, sq = 0.f;
  for (int i = 0; i < 64; ++i){
    float v = xb[(size_t)(fs*64 + i)*W_];
    sum += v; sq += v*v;
  }
  __shared__ float Ssum[4][64], Ssq[4][64], Mu[64], Rs[64];
  Ssum[fs][wl] = sum; Ssq[fs][wl] = sq;
  __syncthreads();
  if (fs == 0){
    float s = Ssum[0][wl]+Ssum[1][wl]+Ssum[2][wl]+Ssum[3][wl];
    float q = Ssq[0][wl]+Ssq[1][wl]+Ssq[2][wl]+Ssq[3][wl];
    float mu = s * (1.f/256.f);
    float var = q * (1.f/256.f) - mu*mu;
    Mu[wl] = mu; Rs[wl] = rsqrtf(var + 1e-5f);
  }
  __syncthreads();
  float mu = Mu[wl], rs = Rs[wl];
  float* yb = Y + (size_t)b*ybs + (size_t)c*FW_ + w;
  for (int i = 0; i < 64; ++i){
    int f = fs*64 + i;
    yb[(size_t)f*W_] = (xb[(size_t)f*W_] - mu)*rs*g[c*F_ + f] + bta[c*F_ + f];
  }
}

// ---------------- fused QKV MFMA GEMM ----------------
// grid (8 w-tiles, 8 g-tiles, 48 = proj*16 + b*8 + c), block 256.
// t[proj][b][c][g][w] = sum_f W[proj][c][g][f] * src[b][c][f][w]
__global__ __launch_bounds__(256)
void gemm_qkv(const float* __restrict__ wq, const float* __restrict__ wk,
              const float* __restrict__ wv,
              const float* __restrict__ srcq, const float* __restrict__ srckv,
              float* __restrict__ T){
  int zid = blockIdx.z;
  int proj = zid >> 4;
  int bc = zid & 15; int b = bc >> 3, c = bc & 7;
  const float* src = (proj == 0) ? srcq : srckv;
  const float* Wm  = (proj == 0) ? wq : (proj == 1 ? wk : wv);
  const float* Ax = src + (size_t)b*CFW_ + (size_t)c*FW_;
  const float* Bw = Wm + (size_t)c*F_*F_;
  float* Yb = T + (size_t)proj*2*CFW_ + (size_t)b*CFW_ + (size_t)c*FW_;

  int w0 = blockIdx.x * 64;
  int g0 = blockIdx.y * 32;
  int t = threadIdx.x, lane = t & 63, wv_ = t >> 6;
  int gq = lane >> 4, c16 = lane & 15;
  int wm = w0 + wv_*16 + c16;
  const f32x4 zero4 = {0.f,0.f,0.f,0.f};
  f32x4 acc[2] = {zero4, zero4};

  for (int k0 = 0; k0 < F_; k0 += 32){
    union { bf16x8 v8; unsigned short u[8]; } af;
    #pragma unroll
    for (int j = 0; j < 8; ++j)
      af.u[j] = f2bf(Ax[(size_t)(k0 + 8*gq + j)*W_ + wm]);
    #pragma unroll
    for (int nf = 0; nf < 2; ++nf){
      union { bf16x8 v8; unsigned short u[8]; } bf;
      const float* bp = Bw + (size_t)(g0 + nf*16 + c16)*F_ + k0 + 8*gq;
      #pragma unroll
      for (int j = 0; j < 8; ++j) bf.u[j] = f2bf(bp[j]);
      acc[nf] = __builtin_amdgcn_mfma_f32_16x16x32_bf16(af.v8, bf.v8, acc[nf], 0, 0, 0);
    }
  }
  int wout = w0 + wv_*16 + 4*gq;
  #pragma unroll
  for (int nf = 0; nf < 2; ++nf){
    float* y = Yb + (size_t)(g0 + nf*16 + c16)*W_ + wout;
    *(float4*)y = make_float4(acc[nf][0], acc[nf][1], acc[nf][2], acc[nf][3]);
  }
}

// ---------------- single MFMA GEMM (batch-strided), optional accumulate -------
// grid (8, 8, 16 = b*8+c)
template<int ACC>
__global__ __launch_bounds__(256)
void gemm_mfma(const float* __restrict__ Wmat,
               const float* __restrict__ X, long xbs,
               float* __restrict__ Y, long ybs){
  int bc = blockIdx.z; int b = bc >> 3, c = bc & 7;
  const float* Ax = X + (size_t)b*xbs + (size_t)c*FW_;
  const float* Bw = Wmat + (size_t)c*F_*F_;
  float* Yb = Y + (size_t)b*ybs + (size_t)c*FW_;
  int w0 = blockIdx.x * 64;
  int g0 = blockIdx.y * 32;
  int t = threadIdx.x, lane = t & 63, wv_ = t >> 6;
  int gq = lane >> 4, c16 = lane & 15;
  int wm = w0 + wv_*16 + c16;
  const f32x4 zero4 = {0.f,0.f,0.f,0.f};
  f32x4 acc[2] = {zero4, zero4};

  for (int k0 = 0; k0 < F_; k0 += 32){
    union { bf16x8 v8; unsigned short u[8]; } af;
    #pragma unroll
    for (int j = 0; j < 8; ++j)
      af.u[j] = f2bf(Ax[(size_t)(k0 + 8*gq + j)*W_ + wm]);
    #pragma unroll
    for (int nf = 0; nf < 2; ++nf){
      union { bf16x8 v8; unsigned short u[8]; } bf;
      const float* bp = Bw + (size_t)(g0 + nf*16 + c16)*F_ + k0 + 8*gq;
      #pragma unroll
      for (int j = 0; j < 8; ++j) bf.u[j] = f2bf(bp[j]);
      acc[nf] = __builtin_amdgcn_mfma_f32_16x16x32_bf16(af.v8, bf.v8, acc[nf], 0, 0, 0);
    }
  }
  int wout = w0 + wv_*16 + 4*gq;
  #pragma unroll
  for (int nf = 0; nf < 2; ++nf){
    float* y = Yb + (size_t)(g0 + nf*16 + c16)*W_ + wout;
    float4 val = make_float4(acc[nf][0], acc[nf][1], acc[nf][2], acc[nf][3]);
    if (ACC){
      float4 o = *(float4*)y;
      val.x += o.x; val.y += o.y; val.z += o.z; val.w += o.w;
    }
    *(float4*)y = val;
  }
}

// ---------------- fused q/k/v channel-mix 1x3 conv (+RoPE for q,k) ------------
// grid 3072, block 256. idx -> (p, b, co, jf, wq); 4 w's per thread.
__global__ __launch_bounds__(256)
void conv_rope3(const float* __restrict__ T,
                const float* __restrict__ Kq3, const float* __restrict__ bq,
                const float* __restrict__ Kk3, const float* __restrict__ bk,
                const float* __restrict__ Kv3, const float* __restrict__ bv,
                float* __restrict__ Q, float* __restrict__ K,
                float* __restrict__ V){
  int idx = blockIdx.x*256 + threadIdx.x;            // 786432
  int wq_ = idx & 127; int r = idx >> 7;
  int jf = r & 127; r >>= 7;
  int co = r & 7; r >>= 3;
  int b = r & 1; int p = r >> 1;                     // proj 0..2 (block-uniform)
  const float* K3   = (p == 0) ? Kq3 : (p == 1 ? Kk3 : Kv3);
  const float* bias = (p == 0) ? bq  : (p == 1 ? bk  : bv);
  const float* Tb = T + (size_t)p*2*CFW_ + (size_t)b*CFW_;
  float* O = ((p == 0) ? Q : (p == 1 ? K : V)) + (size_t)b*CFW_;

  int w0 = wq_*4;
  int f0 = jf*2;
  float bs = bias[co];
  float a0[4] = {bs,bs,bs,bs}, a1[4] = {bs,bs,bs,bs};
  #pragma unroll
  for (int ci = 0; ci < 8; ++ci){
    const float* row0 = Tb + ((size_t)ci*F_ + f0)*W_;
    const float* row1 = row0 + W_;
    const float* kk = K3 + (co*8 + ci)*3;
    float k0 = kk[0], k1 = kk[1], k2 = kk[2];
    float4 m0 = *(const float4*)(row0 + w0);
    float4 m1 = *(const float4*)(row1 + w0);
    float l0 = (w0 > 0) ? row0[w0-1] : 0.f;
    float l1 = (w0 > 0) ? row1[w0-1] : 0.f;
    float e0 = (w0+4 < W_) ? row0[w0+4] : 0.f;
    float e1 = (w0+4 < W_) ? row1[w0+4] : 0.f;
    a0[0] += k0*l0   + k1*m0.x + k2*m0.y;
    a0[1] += k0*m0.x + k1*m0.y + k2*m0.z;
    a0[2] += k0*m0.y + k1*m0.z + k2*m0.w;
    a0[3] += k0*m0.z + k1*m0.w + k2*e0;
    a1[0] += k0*l1   + k1*m1.x + k2*m1.y;
    a1[1] += k0*m1.x + k1*m1.y + k2*m1.z;
    a1[2] += k0*m1.y + k1*m1.z + k2*m1.w;
    a1[3] += k0*m1.z + k1*m1.w + k2*e1;
  }
  size_t obase = ((size_t)co*F_ + f0)*W_ + w0;
  if (p < 2){
    int j = jf & 15;
    float inv = exp2f(-(float)j * 0.83048202372184f);  // 10000^(-j/16)
    float sv, cv, ds, dc;
    sincosf((float)w0 * inv, &sv, &cv);
    sincosf(inv, &ds, &dc);
    float o0[4], o1[4];
    #pragma unroll
    for (int qd = 0; qd < 4; ++qd){
      o0[qd] = a0[qd]*cv - a1[qd]*sv;
      o1[qd] = a1[qd]*cv + a0[qd]*sv;
      float cn = cv*dc - sv*ds;
      sv = sv*dc + cv*ds;
      cv = cn;
    }
    *(float4*)(O + obase)      = make_float4(o0[0], o0[1], o0[2], o0[3]);
    *(float4*)(O + obase + W_) = make_float4(o1[0], o1[1], o1[2], o1[3]);
  } else {
    *(float4*)(O + obase)      = make_float4(a0[0], a0[1], a0[2], a0[3]);
    *(float4*)(O + obase + W_) = make_float4(a1[0], a1[1], a1[2], a1[3]);
  }
}

// ---------------- MFMA attention, batch in grid.x high bits ----------------
// grid (128 = b*64 + c*8 + h, 4 q-tiles), block 512 (8 waves).
__global__ __launch_bounds__(512)
void attn_mfma(const float* __restrict__ q, const float* __restrict__ k,
               const float* __restrict__ v, float* __restrict__ a){
  extern __shared__ __align__(16) unsigned char smem_dyn[];
  unsigned short* ks = (unsigned short*)smem_dyn;   // [512][40]
  unsigned short* vs = ks + 512*40;                 // [32][520]
  unsigned short* ps = vs + 32*520;                 // [8][16][136]
  int bx = blockIdx.x;
  int b = bx >> 6;
  int ch = bx & 63;
  int h = ch & 7, c = ch >> 3;
  size_t base = (size_t)b*CFW_ + ((size_t)c*F_ + h*32)*W_;
  int t = threadIdx.x;
  int lane = t & 63, wv = t >> 6;
  int g = lane >> 4, c16 = lane & 15;

  int q0 = blockIdx.y*128 + wv*16;
  union { bf16x8 v8; unsigned short u[8]; } aq;
  #pragma unroll
  for (int j = 0; j < 8; ++j){
    float qv = q[base + (size_t)(8*g + j)*W_ + q0 + c16] * 0.0625f; // 1/sqrt(256)
    aq.u[j] = f2bf(qv);
  }

  for (int d = 0; d < 32; ++d)
    ks[t*40 + d] = f2bf(k[base + (size_t)d*W_ + t]);       // t = m (512)
  {
    int m2 = t & 255;
    #pragma unroll
    for (int it = 0; it < 16; ++it){
      int d = it*2 + (t >> 8);
      float2 vv = *(const float2*)(v + base + (size_t)d*W_ + 2*m2);
      unsigned pk = ((unsigned)f2bf(vv.y) << 16) | (unsigned)f2bf(vv.x);
      *(unsigned*)(vs + (size_t)d*520 + 2*m2) = pk;
    }
  }
  __syncthreads();

  unsigned short* pw = ps + (size_t)wv*16*136;

  float mrun[4] = {-3e38f,-3e38f,-3e38f,-3e38f};
  float lrun[4] = {0.f,0.f,0.f,0.f};
  const f32x4 zero4 = {0.f,0.f,0.f,0.f};
  f32x4 outacc[2] = {zero4, zero4};

  for (int kt = 0; kt < 4; ++kt){
    f32x4 sv[8];
    #pragma unroll
    for (int mi = 0; mi < 8; ++mi){
      int m0 = kt*128 + mi*16;
      bf16x8 kb8 = *(const bf16x8*)(ks + (size_t)(m0 + c16)*40 + 8*g);
      sv[mi] = __builtin_amdgcn_mfma_f32_16x16x32_bf16(aq.v8, kb8, zero4, 0, 0, 0);
    }
    float pmax[4];
    #pragma unroll
    for (int r = 0; r < 4; ++r){
      float m = sv[0][r];
      #pragma unroll
      for (int mi = 1; mi < 8; ++mi) m = fmaxf(m, sv[mi][r]);
      pmax[r] = m;
    }
    #pragma unroll
    for (int mask = 1; mask <= 8; mask <<= 1){
      #pragma unroll
      for (int r = 0; r < 4; ++r)
        pmax[r] = fmaxf(pmax[r], __shfl_xor(pmax[r], mask));
    }
    float corr[4];
    #pragma unroll
    for (int r = 0; r < 4; ++r){
      float mn = fmaxf(mrun[r], pmax[r]);
      corr[r] = __expf(mrun[r] - mn);
      mrun[r] = mn;
      lrun[r] *= corr[r];
    }
    #pragma unroll
    for (int mi = 0; mi < 8; ++mi){
      #pragma unroll
      for (int r = 0; r < 4; ++r){
        float p = __expf(sv[mi][r] - mrun[r]);
        lrun[r] += p;
        pw[(size_t)(4*g + r)*136 + mi*16 + c16] = f2bf(p);
      }
    }
    f32x4 cv = {corr[0], corr[1], corr[2], corr[3]};
    outacc[0] *= cv;
    outacc[1] *= cv;
    #pragma unroll
    for (int mc = 0; mc < 4; ++mc){
      bf16x8 pa  = *(const bf16x8*)(pw + (size_t)c16*136 + mc*32 + 8*g);
      bf16x8 vb0 = *(const bf16x8*)(vs + (size_t)c16*520      + kt*128 + mc*32 + 8*g);
      bf16x8 vb1 = *(const bf16x8*)(vs + (size_t)(16+c16)*520 + kt*128 + mc*32 + 8*g);
      outacc[0] = __builtin_amdgcn_mfma_f32_16x16x32_bf16(pa, vb0, outacc[0], 0, 0, 0);
      outacc[1] = __builtin_amdgcn_mfma_f32_16x16x32_bf16(pa, vb1, outacc[1], 0, 0, 0);
    }
  }
  float L[4];
  #pragma unroll
  for (int r = 0; r < 4; ++r){
    float s = lrun[r];
    #pragma unroll
    for (int mask = 1; mask <= 8; mask <<= 1) s += __shfl_xor(s, mask);
    L[r] = s;
  }
  #pragma unroll
  for (int dt = 0; dt < 2; ++dt){
    #pragma unroll
    for (int r = 0; r < 4; ++r)
      a[base + (size_t)(dt*16 + c16)*W_ + q0 + 4*g + r] = outacc[dt][r] / L[r];
  }
}

// ---------------- depthwise feature convs (batch-strided) ----------------
// grid (2, 256, 16 = b*8+c)
__global__ __launch_bounds__(256)
void dw_fuse_b(const float* __restrict__ Z, long zbs,
               const float* __restrict__ k11, const float* __restrict__ b11,
               const float* __restrict__ k7,  const float* __restrict__ b7,
               float* __restrict__ S, long sbs){
  int w = blockIdx.x*256 + threadIdx.x;
  int f = blockIdx.y;
  int bc = blockIdx.z; int b = bc >> 3, c = bc & 7;
  const float* zb = Z + (size_t)b*zbs + (size_t)c*FW_;
  float a = b11[c];
  #pragma unroll
  for (int i = 0; i < 11; ++i){
    int ff = f - 5 + i;
    if (ff >= 0 && ff < F_) a += k11[c*11 + i]*zb[(size_t)ff*W_ + w];
  }
  float bb = b7[c];
  #pragma unroll
  for (int i = 0; i < 7; ++i){
    int ff = f - 3 + i;
    if (ff >= 0 && ff < F_) bb += k7[c*7 + i]*zb[(size_t)ff*W_ + w];
  }
  float ra = a > 0.f ? a*a : 0.f;
  S[(size_t)b*sbs + ((size_t)c*F_ + f)*W_ + w] = ra + bb;
}

__global__ __launch_bounds__(256)
void conv7_add_b(const float* __restrict__ T, long tbs,
                 const float* __restrict__ k7, const float* __restrict__ b7,
                 float* __restrict__ Hp, long hbs){
  int w = blockIdx.x*256 + threadIdx.x;
  int f = blockIdx.y;
  int bc = blockIdx.z; int b = bc >> 3, c = bc & 7;
  const float* tb = T + (size_t)b*tbs + (size_t)c*FW_;
  float acc = b7[c];
  #pragma unroll
  for (int i = 0; i < 7; ++i){
    int ff = f - 3 + i;
    if (ff >= 0 && ff < F_) acc += k7[c*7 + i]*tb[(size_t)ff*W_ + w];
  }
  Hp[(size_t)b*hbs + ((size_t)c*F_ + f)*W_ + w] += acc;
}

// ---------------- tiny FF: H += w4 @ sq_relu(w3 @ Z) ----------------
// grid (8, 8, 2), block 256
__global__ __launch_bounds__(256)
void ff_b2(const float* __restrict__ Z, long zbs,
           const float* __restrict__ w3, const float* __restrict__ w4,
           float* __restrict__ Hp, long hbs){
  int wl = threadIdx.x & 63, fs = threadIdx.x >> 6;
  int w = blockIdx.x*64 + wl;
  int c = blockIdx.y;
  int b = blockIdx.z;
  const float* zb = Z + (size_t)b*zbs + (size_t)c*FW_ + w;
  float u[4] = {0.f,0.f,0.f,0.f};
  for (int i = 0; i < 64; ++i){
    int f = fs*64 + i;
    float zv = zb[(size_t)f*W_];
    #pragma unroll
    for (int e = 0; e < 4; ++e) u[e] += w3[(c*4 + e)*F_ + f]*zv;
  }
  __shared__ float Us[4][4][64];
  #pragma unroll
  for (int e = 0; e < 4; ++e) Us[fs][e][wl] = u[e];
  __syncthreads();
  float uf[4];
  #pragma unroll
  for (int e = 0; e < 4; ++e){
    float s = Us[0][e][wl] + Us[1][e][wl] + Us[2][e][wl] + Us[3][e][wl];
    float rr = s > 0.f ? s : 0.f;
    uf[e] = rr*rr;
  }
  float* hb = Hp + (size_t)b*hbs + (size_t)c*FW_ + w;
  for (int i = 0; i < 64; ++i){
    int f = fs*64 + i;
    const float* w4r = w4 + (c*F_ + f)*4;
    hb[(size_t)f*W_] += w4r[0]*uf[0] + w4r[1]*uf[1] + w4r[2]*uf[2] + w4r[3]*uf[3];
  }
}

extern "C" void kernel_launch(void* const* d_in, const int* in_sizes, int n_in,
                              void* d_out, int out_size, void* d_ws, size_t ws_size,
                              hipStream_t stream){
  const float* x    = (const float*)d_in[0];
  const float* skip = (const float*)d_in[1];
  const float* Wq   = (const float*)d_in[2];
  const float* Kq   = (const float*)d_in[3];
  const float* bq   = (const float*)d_in[4];
  const float* Wk   = (const float*)d_in[5];
  const float* Kk   = (const float*)d_in[6];
  const float* bk   = (const float*)d_in[7];
  const float* Wv   = (const float*)d_in[8];
  const float* Kv   = (const float*)d_in[9];
  const float* bv   = (const float*)d_in[10];
  const float* Wo   = (const float*)d_in[11];
  const float* ng   = (const float*)d_in[12];
  const float* nb   = (const float*)d_in[13];
  const float* c1aw = (const float*)d_in[14];
  const float* c1ab = (const float*)d_in[15];
  const float* c1bw = (const float*)d_in[16];
  const float* c1bb = (const float*)d_in[17];
  const float* c2w  = (const float*)d_in[18];
  const float* c2b  = (const float*)d_in[19];
  const float* w3   = (const float*)d_in[20];
  const float* w4   = (const float*)d_in[21];

  float* out = (float*)d_out;
  float* hp  = out + CFW_;           // h at hp + b*OBS_ + c*FW_

  // ws buffers (floats), 14*CFW total = 58,720,256 B (ws ≈ 256 MiB per profile)
  float* ws = (float*)d_ws;
  float* zb = ws;                    // z: 2*CFW (batch stride CFW)
  float* tb = ws + (size_t)2*CFW_;   // t0,t1,t2: 6*CFW; t0 reused as attn out
  float* qb = ws + (size_t)8*CFW_;   // q: 2*CFW (ln2 output reuses this)
  float* kb = ws + (size_t)10*CFW_;  // k: 2*CFW
  float* vb = ws + (size_t)12*CFW_;  // v: 2*CFW

  float code = 0.f;
  if (n_in != 22) code += 20000.f;
  if (out_size != 4194304) code += 80000.f;
  if (ws_size < (size_t)14*CFW_*4) code += 160000.f;

  dim3 gPix(2, F_, 16);
  dim3 gGemmQKV(8, 8, 48);
  dim3 gGemmWo(8, 8, 16);
  dim3 gLn(8, 8, 2);
  dim3 gAttn(128, 4);
  const int attn_lds_bytes = (512*40 + 32*520 + 8*16*136) * 2;  // 109056

  init_out<<<8192, 256, 0, stream>>>(x, out);

  auto do_attn = [&](int i, const float* srcq, const float* srckv){
    gemm_qkv<<<gGemmQKV, 256, 0, stream>>>(
        Wq + (size_t)i*C_*F_*F_, Wk + (size_t)i*C_*F_*F_, Wv + (size_t)i*C_*F_*F_,
        srcq, srckv, tb);
    conv_rope3<<<3072, 256, 0, stream>>>(
        tb, Kq + i*C_*C_*3, bq + i*C_, Kk + i*C_*C_*3, bk + i*C_,
        Kv + i*C_*C_*3, bv + i*C_, qb, kb, vb);
    attn_mfma<<<gAttn, 512, attn_lds_bytes, stream>>>(qb, kb, vb, tb);
    gemm_mfma<1><<<gGemmWo, 256, 0, stream>>>(Wo + (size_t)i*C_*F_*F_,
                                              tb, CFW_, hp, OBS_);
  };

  // z = LN0(x); h = x + att0(z,z) + att1(z,skip)   (z persists now)
  ln4_b<<<gLn, 256, 0, stream>>>(x, CFW_, zb, CFW_, ng + 0*C_*F_, nb + 0*C_*F_);
  do_attn(0, zb, zb);
  do_attn(1, zb, skip);

  // conv block
  ln4_b<<<gLn, 256, 0, stream>>>(hp, OBS_, zb, CFW_, ng + 1*C_*F_, nb + 1*C_*F_);
  dw_fuse_b<<<gPix, 256, 0, stream>>>(zb, CFW_, c1aw, c1ab, c1bw, c1bb, tb, CFW_);
  ln4_b<<<gLn, 256, 0, stream>>>(tb, CFW_, qb, CFW_, ng + 2*C_*F_, nb + 2*C_*F_);
  conv7_add_b<<<gPix, 256, 0, stream>>>(qb, CFW_, c2w, c2b, hp, OBS_);

  // att2 (self on LN3(h))
  ln4_b<<<gLn, 256, 0, stream>>>(hp, OBS_, zb, CFW_, ng + 3*C_*F_, nb + 3*C_*F_);
  do_attn(2, zb, zb);

  // att3 (LN4(h) vs skip)
  ln4_b<<<gLn, 256, 0, stream>>>(hp, OBS_, zb, CFW_, ng + 4*C_*F_, nb + 4*C_*F_);
  do_attn(3, zb, skip);

  // FF
  ln4_b<<<gLn, 256, 0, stream>>>(hp, OBS_, zb, CFW_, ng + 5*C_*F_, nb + 5*C_*F_);
  ff_b2<<<gLn, 256, 0, stream>>>(zb, CFW_, w3, w4, hp, OBS_);

  if (code != 0.f) put_val<<<1, 1, 0, stream>>>(out, code);
}

// Round 12
// 492.917 us; speedup vs baseline: 25.7029x; 1.2445x over previous
//
#include <hip/hip_runtime.h>

#define B_ 2
#define C_ 8
#define F_ 256
#define W_ 512
#define H_ 8
#define FW_ (F_*W_)        // 131072
#define CFW_ (C_*FW_)      // 1048576 = one batch of (C,F,W)
#define OBS_ (2*CFW_)      // out batch stride (B,16,F,W)

typedef unsigned short u16;

__device__ __forceinline__ u16 f2bf(float f){
  unsigned u = __float_as_uint(f);
  u += 0x7fffu + ((u>>16)&1u);
  return (u16)(u>>16);
}
__device__ __forceinline__ float bf2f(u16 u){
  return __uint_as_float((unsigned)u<<16);
}

typedef __attribute__((ext_vector_type(8))) short bf16x8;
typedef __attribute__((ext_vector_type(4))) float f32x4;

// ---------------- init: both halves of out = x ----------------
__global__ __launch_bounds__(256)
void init_out(const float* __restrict__ x, float* __restrict__ out){
  int i = blockIdx.x*256 + threadIdx.x;              // 2M
  int b = i >> 20;
  int r = i & (CFW_-1);
  float v = x[i];
  out[(size_t)b*OBS_ + r] = v;
  out[(size_t)b*OBS_ + CFW_ + r] = v;
}

__global__ void put_val(float* o, float v){ o[0] = v; }

// ---------------- bulk f32 -> bf16 conversion (5 arrays of 2,097,152) --------
__global__ __launch_bounds__(256)
void cvt5(const float* __restrict__ s0, const float* __restrict__ s1,
          const float* __restrict__ s2, const float* __restrict__ s3,
          const float* __restrict__ s4,
          u16* __restrict__ d0, u16* __restrict__ d1, u16* __restrict__ d2,
          u16* __restrict__ d3, u16* __restrict__ d4){
  int which = blockIdx.y;
  const float* s = which==0 ? s0 : which==1 ? s1 : which==2 ? s2 : which==3 ? s3 : s4;
  u16* d        = which==0 ? d0 : which==1 ? d1 : which==2 ? d2 : which==3 ? d3 : d4;
  int i = (blockIdx.x*256 + threadIdx.x)*4;          // 2048 blocks x 1024 elems
  float4 v = *(const float4*)(s + i);
  ushort4 o;
  o.x = f2bf(v.x); o.y = f2bf(v.y); o.z = f2bf(v.z); o.w = f2bf(v.w);
  *(ushort4*)(d + i) = o;
}

// ---------------- LayerNorm over f -> f32 out (conv/FF path) ----------------
// grid (8, 8, 2), block 256
__global__ __launch_bounds__(256)
void ln4_b(const float* __restrict__ X, long xbs, float* __restrict__ Y, long ybs,
           const float* __restrict__ g, const float* __restrict__ bta){
  int wl = threadIdx.x & 63, fs = threadIdx.x >> 6;
  int w = blockIdx.x*64 + wl;
  int c = blockIdx.y;
  int b = blockIdx.z;
  const float* xb = X + (size_t)b*xbs + (size_t)c*FW_ + w;
  float sum = 0.f, sq = 0.f;
  for (int i = 0; i < 64; ++i){
    float v = xb[(size_t)(fs*64 + i)*W_];
    sum += v; sq += v*v;
  }
  __shared__ float Ssum[4][64], Ssq[4][64], Mu[64], Rs[64];
  Ssum[fs][wl] = sum; Ssq[fs][wl] = sq;
  __syncthreads();
  if (fs == 0){
    float s = Ssum[0][wl]+Ssum[1][wl]+Ssum[2][wl]+Ssum[3][wl];
    float q = Ssq[0][wl]+Ssq[1][wl]+Ssq[2][wl]+Ssq[3][wl];
    float mu = s * (1.f/256.f);
    float var = q * (1.f/256.f) - mu*mu;
    Mu[wl] = mu; Rs[wl] = rsqrtf(var + 1e-5f);
  }
  __syncthreads();
  float mu = Mu[wl], rs = Rs[wl];
  float* yb = Y + (size_t)b*ybs + (size_t)c*FW_ + w;
  for (int i = 0; i < 64; ++i){
    int f = fs*64 + i;
    yb[(size_t)f*W_] = (xb[(size_t)f*W_] - mu)*rs*g[c*F_ + f] + bta[c*F_ + f];
  }
}

// ---------------- LayerNorm over f -> bf16 out (attention path) --------------
__global__ __launch_bounds__(256)
void ln4_h(const float* __restrict__ X, long xbs, u16* __restrict__ Y, long ybs,
           const float* __restrict__ g, const float* __restrict__ bta){
  int wl = threadIdx.x & 63, fs = threadIdx.x >> 6;
  int w = blockIdx.x*64 + wl;
  int c = blockIdx.y;
  int b = blockIdx.z;
  const float* xb = X + (size_t)b*xbs + (size_t)c*FW_ + w;
  float sum = 0.f, sq = 0.f;
  for (int i = 0; i < 64; ++i){
    float v = xb[(size_t)(fs*64 + i)*W_];
    sum += v; sq += v*v;
  }
  __shared__ float Ssum[4][64], Ssq[4][64], Mu[64], Rs[64];
  Ssum[fs][wl] = sum; Ssq[fs][wl] = sq;
  __syncthreads();
  if (fs == 0){
    float s = Ssum[0][wl]+Ssum[1][wl]+Ssum[2][wl]+Ssum[3][wl];
    float q = Ssq[0][wl]+Ssq[1][wl]+Ssq[2][wl]+Ssq[3][wl];
    float mu = s * (1.f/256.f);
    float var = q * (1.f/256.f) - mu*mu;
    Mu[wl] = mu; Rs[wl] = rsqrtf(var + 1e-5f);
  }
  __syncthreads();
  float mu = Mu[wl], rs = Rs[wl];
  u16* yb = Y + (size_t)b*ybs + (size_t)c*FW_ + w;
  for (int i = 0; i < 64; ++i){
    int f = fs*64 + i;
    yb[(size_t)f*W_] = f2bf((xb[(size_t)f*W_] - mu)*rs*g[c*F_ + f] + bta[c*F_ + f]);
  }
}

// ---------------- fused QKV MFMA GEMM, all-bf16 ----------------
// grid (8 w-tiles, 4 g-tiles(64), 48 = proj*16+b*8+c), block 256.
__global__ __launch_bounds__(256)
void gemm_qkv_b(const u16* __restrict__ wqb, const u16* __restrict__ wkb,
                const u16* __restrict__ wvb,
                const u16* __restrict__ srcq, const u16* __restrict__ srckv,
                u16* __restrict__ T){
  int zid = blockIdx.z;
  int proj = zid >> 4;
  int bc = zid & 15; int b = bc >> 3, c = bc & 7;
  const u16* src = (proj == 0) ? srcq : srckv;
  const u16* Wm  = (proj == 0) ? wqb : (proj == 1 ? wkb : wvb);
  const u16* Ax = src + (size_t)b*CFW_ + (size_t)c*FW_;
  const u16* Bw = Wm + (size_t)c*F_*F_;
  u16* Yb = T + (size_t)proj*2*CFW_ + (size_t)b*CFW_ + (size_t)c*FW_;

  int w0 = blockIdx.x * 64;
  int g0 = blockIdx.y * 64;
  int t = threadIdx.x, lane = t & 63, wv_ = t >> 6;
  int gq = lane >> 4, c16 = lane & 15;
  int wm = w0 + wv_*16 + c16;
  const f32x4 zero4 = {0.f,0.f,0.f,0.f};
  f32x4 acc[4] = {zero4, zero4, zero4, zero4};

  for (int k0 = 0; k0 < F_; k0 += 32){
    union { bf16x8 v8; u16 u[8]; } af;
    #pragma unroll
    for (int j = 0; j < 8; ++j)
      af.u[j] = Ax[(size_t)(k0 + 8*gq + j)*W_ + wm];
    #pragma unroll
    for (int nf = 0; nf < 4; ++nf){
      bf16x8 bfr = *(const bf16x8*)(Bw + (size_t)(g0 + nf*16 + c16)*F_ + k0 + 8*gq);
      acc[nf] = __builtin_amdgcn_mfma_f32_16x16x32_bf16(af.v8, bfr, acc[nf], 0, 0, 0);
    }
  }
  int wout = w0 + wv_*16 + 4*gq;
  #pragma unroll
  for (int nf = 0; nf < 4; ++nf){
    ushort4 o;
    o.x = f2bf(acc[nf][0]); o.y = f2bf(acc[nf][1]);
    o.z = f2bf(acc[nf][2]); o.w = f2bf(acc[nf][3]);
    *(ushort4*)(Yb + (size_t)(g0 + nf*16 + c16)*W_ + wout) = o;
  }
}

// ---------------- Wo MFMA GEMM: h(f32) += a(bf16) @ Wo(bf16) ----------------
// grid (8, 4, 16 = b*8+c), block 256
__global__ __launch_bounds__(256)
void gemm_wo_b(const u16* __restrict__ wob, const u16* __restrict__ A,
               float* __restrict__ Y){
  int bc = blockIdx.z; int b = bc >> 3, c = bc & 7;
  const u16* Ax = A + (size_t)b*CFW_ + (size_t)c*FW_;
  const u16* Bw = wob + (size_t)c*F_*F_;
  float* Yb = Y + (size_t)b*OBS_ + (size_t)c*FW_;
  int w0 = blockIdx.x * 64;
  int g0 = blockIdx.y * 64;
  int t = threadIdx.x, lane = t & 63, wv_ = t >> 6;
  int gq = lane >> 4, c16 = lane & 15;
  int wm = w0 + wv_*16 + c16;
  const f32x4 zero4 = {0.f,0.f,0.f,0.f};
  f32x4 acc[4] = {zero4, zero4, zero4, zero4};

  for (int k0 = 0; k0 < F_; k0 += 32){
    union { bf16x8 v8; u16 u[8]; } af;
    #pragma unroll
    for (int j = 0; j < 8; ++j)
      af.u[j] = Ax[(size_t)(k0 + 8*gq + j)*W_ + wm];
    #pragma unroll
    for (int nf = 0; nf < 4; ++nf){
      bf16x8 bfr = *(const bf16x8*)(Bw + (size_t)(g0 + nf*16 + c16)*F_ + k0 + 8*gq);
      acc[nf] = __builtin_amdgcn_mfma_f32_16x16x32_bf16(af.v8, bfr, acc[nf], 0, 0, 0);
    }
  }
  int wout = w0 + wv_*16 + 4*gq;
  #pragma unroll
  for (int nf = 0; nf < 4; ++nf){
    float* y = Yb + (size_t)(g0 + nf*16 + c16)*W_ + wout;
    float4 o = *(float4*)y;
    o.x += acc[nf][0]; o.y += acc[nf][1]; o.z += acc[nf][2]; o.w += acc[nf][3];
    *(float4*)y = o;
  }
}

// ---------------- fused q/k/v 1x3 conv (+RoPE, q pre-scaled), bf16 I/O -------
// grid 3072, block 256. idx -> (p, b, co, jf, wq); 4 w's per thread.
__global__ __launch_bounds__(256)
void conv_rope3_b(const u16* __restrict__ T,
                  const float* __restrict__ Kq3, const float* __restrict__ bq,
                  const float* __restrict__ Kk3, const float* __restrict__ bk,
                  const float* __restrict__ Kv3, const float* __restrict__ bv,
                  u16* __restrict__ Q, u16* __restrict__ K,
                  u16* __restrict__ V){
  int idx = blockIdx.x*256 + threadIdx.x;            // 786432
  int wq_ = idx & 127; int r = idx >> 7;
  int jf = r & 127; r >>= 7;
  int co = r & 7; r >>= 3;
  int b = r & 1; int p = r >> 1;                     // proj 0..2 (block-uniform)
  const float* K3   = (p == 0) ? Kq3 : (p == 1 ? Kk3 : Kv3);
  const float* bias = (p == 0) ? bq  : (p == 1 ? bk  : bv);
  const u16* Tb = T + (size_t)p*2*CFW_ + (size_t)b*CFW_;
  u16* O = ((p == 0) ? Q : (p == 1 ? K : V)) + (size_t)b*CFW_;

  int w0 = wq_*4;
  int f0 = jf*2;
  float bs = bias[co];
  float a0[4] = {bs,bs,bs,bs}, a1[4] = {bs,bs,bs,bs};
  #pragma unroll
  for (int ci = 0; ci < 8; ++ci){
    const u16* row0 = Tb + ((size_t)ci*F_ + f0)*W_;
    const u16* row1 = row0 + W_;
    const float* kk = K3 + (co*8 + ci)*3;
    float k0 = kk[0], k1 = kk[1], k2 = kk[2];
    ushort4 r0 = *(const ushort4*)(row0 + w0);
    ushort4 r1 = *(const ushort4*)(row1 + w0);
    float m0x = bf2f(r0.x), m0y = bf2f(r0.y), m0z = bf2f(r0.z), m0w = bf2f(r0.w);
    float m1x = bf2f(r1.x), m1y = bf2f(r1.y), m1z = bf2f(r1.z), m1w = bf2f(r1.w);
    float l0 = (w0 > 0) ? bf2f(row0[w0-1]) : 0.f;
    float l1 = (w0 > 0) ? bf2f(row1[w0-1]) : 0.f;
    float e0 = (w0+4 < W_) ? bf2f(row0[w0+4]) : 0.f;
    float e1 = (w0+4 < W_) ? bf2f(row1[w0+4]) : 0.f;
    a0[0] += k0*l0  + k1*m0x + k2*m0y;
    a0[1] += k0*m0x + k1*m0y + k2*m0z;
    a0[2] += k0*m0y + k1*m0z + k2*m0w;
    a0[3] += k0*m0z + k1*m0w + k2*e0;
    a1[0] += k0*l1  + k1*m1x + k2*m1y;
    a1[1] += k0*m1x + k1*m1y + k2*m1z;
    a1[2] += k0*m1y + k1*m1z + k2*m1w;
    a1[3] += k0*m1z + k1*m1w + k2*e1;
  }
  size_t obase = ((size_t)co*F_ + f0)*W_ + w0;
  if (p < 2){
    int j = jf & 15;
    float inv = exp2f(-(float)j * 0.83048202372184f);  // 10000^(-j/16)
    float sv, cv, ds, dc;
    sincosf((float)w0 * inv, &sv, &cv);
    sincosf(inv, &ds, &dc);
    float scale = (p == 0) ? 0.0625f : 1.f;           // fold 1/sqrt(256) into q
    float o0[4], o1[4];
    #pragma unroll
    for (int qd = 0; qd < 4; ++qd){
      o0[qd] = (a0[qd]*cv - a1[qd]*sv)*scale;
      o1[qd] = (a1[qd]*cv + a0[qd]*sv)*scale;
      float cn = cv*dc - sv*ds;
      sv = sv*dc + cv*ds;
      cv = cn;
    }
    ushort4 p0, p1;
    p0.x = f2bf(o0[0]); p0.y = f2bf(o0[1]); p0.z = f2bf(o0[2]); p0.w = f2bf(o0[3]);
    p1.x = f2bf(o1[0]); p1.y = f2bf(o1[1]); p1.z = f2bf(o1[2]); p1.w = f2bf(o1[3]);
    *(ushort4*)(O + obase)      = p0;
    *(ushort4*)(O + obase + W_) = p1;
  } else {
    ushort4 p0, p1;
    p0.x = f2bf(a0[0]); p0.y = f2bf(a0[1]); p0.z = f2bf(a0[2]); p0.w = f2bf(a0[3]);
    p1.x = f2bf(a1[0]); p1.y = f2bf(a1[1]); p1.z = f2bf(a1[2]); p1.w = f2bf(a1[3]);
    *(ushort4*)(O + obase)      = p0;
    *(ushort4*)(O + obase + W_) = p1;
  }
}

// ---------------- MFMA attention, bf16 I/O ----------------
// grid (128 = b*64 + c*8 + h, 4 q-tiles), block 512 (8 waves).
// q is pre-scaled by 1/sqrt(256) at the producer.
__global__ __launch_bounds__(512)
void attn_mfma_b(const u16* __restrict__ q, const u16* __restrict__ k,
                 const u16* __restrict__ v, u16* __restrict__ a){
  extern __shared__ __align__(16) unsigned char smem_dyn[];
  u16* ks = (u16*)smem_dyn;          // [512][40]
  u16* vs = ks + 512*40;             // [32][520]
  u16* ps = vs + 32*520;             // [8][16][136]
  int bx = blockIdx.x;
  int b = bx >> 6;
  int ch = bx & 63;
  int h = ch & 7, c = ch >> 3;
  size_t base = (size_t)b*CFW_ + ((size_t)c*F_ + h*32)*W_;
  int t = threadIdx.x;
  int lane = t & 63, wv = t >> 6;
  int g = lane >> 4, c16 = lane & 15;

  int q0 = blockIdx.y*128 + wv*16;
  union { bf16x8 v8; u16 u[8]; } aq;
  #pragma unroll
  for (int j = 0; j < 8; ++j)
    aq.u[j] = q[base + (size_t)(8*g + j)*W_ + q0 + c16];

  for (int d = 0; d < 32; ++d)
    ks[t*40 + d] = k[base + (size_t)d*W_ + t];       // t = m (512)
  {
    int m8 = (t & 63)*8;
    #pragma unroll
    for (int it = 0; it < 4; ++it){
      int d = (t >> 6) + it*8;
      *(uint4*)(vs + (size_t)d*520 + m8) = *(const uint4*)(v + base + (size_t)d*W_ + m8);
    }
  }
  __syncthreads();

  u16* pw = ps + (size_t)wv*16*136;

  float mrun[4] = {-3e38f,-3e38f,-3e38f,-3e38f};
  float lrun[4] = {0.f,0.f,0.f,0.f};
  const f32x4 zero4 = {0.f,0.f,0.f,0.f};
  f32x4 outacc[2] = {zero4, zero4};

  for (int kt = 0; kt < 4; ++kt){
    f32x4 sv[8];
    #pragma unroll
    for (int mi = 0; mi < 8; ++mi){
      int m0 = kt*128 + mi*16;
      bf16x8 kb8 = *(const bf16x8*)(ks + (size_t)(m0 + c16)*40 + 8*g);
      sv[mi] = __builtin_amdgcn_mfma_f32_16x16x32_bf16(aq.v8, kb8, zero4, 0, 0, 0);
    }
    float pmax[4];
    #pragma unroll
    for (int r = 0; r < 4; ++r){
      float m = sv[0][r];
      #pragma unroll
      for (int mi = 1; mi < 8; ++mi) m = fmaxf(m, sv[mi][r]);
      pmax[r] = m;
    }
    #pragma unroll
    for (int mask = 1; mask <= 8; mask <<= 1){
      #pragma unroll
      for (int r = 0; r < 4; ++r)
        pmax[r] = fmaxf(pmax[r], __shfl_xor(pmax[r], mask));
    }
    float corr[4];
    #pragma unroll
    for (int r = 0; r < 4; ++r){
      float mn = fmaxf(mrun[r], pmax[r]);
      corr[r] = __expf(mrun[r] - mn);
      mrun[r] = mn;
      lrun[r] *= corr[r];
    }
    #pragma unroll
    for (int mi = 0; mi < 8; ++mi){
      #pragma unroll
      for (int r = 0; r < 4; ++r){
        float p = __expf(sv[mi][r] - mrun[r]);
        lrun[r] += p;
        pw[(size_t)(4*g + r)*136 + mi*16 + c16] = f2bf(p);
      }
    }
    f32x4 cv = {corr[0], corr[1], corr[2], corr[3]};
    outacc[0] *= cv;
    outacc[1] *= cv;
    #pragma unroll
    for (int mc = 0; mc < 4; ++mc){
      bf16x8 pa  = *(const bf16x8*)(pw + (size_t)c16*136 + mc*32 + 8*g);
      bf16x8 vb0 = *(const bf16x8*)(vs + (size_t)c16*520      + kt*128 + mc*32 + 8*g);
      bf16x8 vb1 = *(const bf16x8*)(vs + (size_t)(16+c16)*520 + kt*128 + mc*32 + 8*g);
      outacc[0] = __builtin_amdgcn_mfma_f32_16x16x32_bf16(pa, vb0, outacc[0], 0, 0, 0);
      outacc[1] = __builtin_amdgcn_mfma_f32_16x16x32_bf16(pa, vb1, outacc[1], 0, 0, 0);
    }
  }
  float L[4];
  #pragma unroll
  for (int r = 0; r < 4; ++r){
    float s = lrun[r];
    #pragma unroll
    for (int mask = 1; mask <= 8; mask <<= 1) s += __shfl_xor(s, mask);
    L[r] = s;
  }
  #pragma unroll
  for (int dt = 0; dt < 2; ++dt){
    ushort4 o;
    o.x = f2bf(outacc[dt][0] / L[0]);
    o.y = f2bf(outacc[dt][1] / L[1]);
    o.z = f2bf(outacc[dt][2] / L[2]);
    o.w = f2bf(outacc[dt][3] / L[3]);
    *(ushort4*)(a + base + (size_t)(dt*16 + c16)*W_ + q0 + 4*g) = o;
  }
}

// ---------------- depthwise feature convs (f32, batch-strided) ----------------
// grid (2, 256, 16 = b*8+c)
__global__ __launch_bounds__(256)
void dw_fuse_b(const float* __restrict__ Z, long zbs,
               const float* __restrict__ k11, const float* __restrict__ b11,
               const float* __restrict__ k7,  const float* __restrict__ b7,
               float* __restrict__ S, long sbs){
  int w = blockIdx.x*256 + threadIdx.x;
  int f = blockIdx.y;
  int bc = blockIdx.z; int b = bc >> 3, c = bc & 7;
  const float* zb = Z + (size_t)b*zbs + (size_t)c*FW_;
  float a = b11[c];
  #pragma unroll
  for (int i = 0; i < 11; ++i){
    int ff = f - 5 + i;
    if (ff >= 0 && ff < F_) a += k11[c*11 + i]*zb[(size_t)ff*W_ + w];
  }
  float bb = b7[c];
  #pragma unroll
  for (int i = 0; i < 7; ++i){
    int ff = f - 3 + i;
    if (ff >= 0 && ff < F_) bb += k7[c*7 + i]*zb[(size_t)ff*W_ + w];
  }
  float ra = a > 0.f ? a*a : 0.f;
  S[(size_t)b*sbs + ((size_t)c*F_ + f)*W_ + w] = ra + bb;
}

__global__ __launch_bounds__(256)
void conv7_add_b(const float* __restrict__ T, long tbs,
                 const float* __restrict__ k7, const float* __restrict__ b7,
                 float* __restrict__ Hp, long hbs){
  int w = blockIdx.x*256 + threadIdx.x;
  int f = blockIdx.y;
  int bc = blockIdx.z; int b = bc >> 3, c = bc & 7;
  const float* tb = T + (size_t)b*tbs + (size_t)c*FW_;
  float acc = b7[c];
  #pragma unroll
  for (int i = 0; i < 7; ++i){
    int ff = f - 3 + i;
    if (ff >= 0 && ff < F_) acc += k7[c*7 + i]*tb[(size_t)ff*W_ + w];
  }
  Hp[(size_t)b*hbs + ((size_t)c*F_ + f)*W_ + w] += acc;
}

// ---------------- tiny FF: H += w4 @ sq_relu(w3 @ Z) ----------------
// grid (8, 8, 2), block 256
__global__ __launch_bounds__(256)
void ff_b2(const float* __restrict__ Z, long zbs,
           const float* __restrict__ w3, const float* __restrict__ w4,
           float* __restrict__ Hp, long hbs){
  int wl = threadIdx.x & 63, fs = threadIdx.x >> 6;
  int w = blockIdx.x*64 + wl;
  int c = blockIdx.y;
  int b = blockIdx.z;
  const float* zb = Z + (size_t)b*zbs + (size_t)c*FW_ + w;
  float u[4] = {0.f,0.f,0.f,0.f};
  for (int i = 0; i < 64; ++i){
    int f = fs*64 + i;
    float zv = zb[(size_t)f*W_];
    #pragma unroll
    for (int e = 0; e < 4; ++e) u[e] += w3[(c*4 + e)*F_ + f]*zv;
  }
  __shared__ float Us[4][4][64];
  #pragma unroll
  for (int e = 0; e < 4; ++e) Us[fs][e][wl] = u[e];
  __syncthreads();
  float uf[4];
  #pragma unroll
  for (int e = 0; e < 4; ++e){
    float s = Us[0][e][wl] + Us[1][e][wl] + Us[2][e][wl] + Us[3][e][wl];
    float rr = s > 0.f ? s : 0.f;
    uf[e] = rr*rr;
  }
  float* hb = Hp + (size_t)b*hbs + (size_t)c*FW_ + w;
  for (int i = 0; i < 64; ++i){
    int f = fs*64 + i;
    const float* w4r = w4 + (c*F_ + f)*4;
    hb[(size_t)f*W_] += w4r[0]*uf[0] + w4r[1]*uf[1] + w4r[2]*uf[2] + w4r[3]*uf[3];
  }
}

extern "C" void kernel_launch(void* const* d_in, const int* in_sizes, int n_in,
                              void* d_out, int out_size, void* d_ws, size_t ws_size,
                              hipStream_t stream){
  const float* x    = (const float*)d_in[0];
  const float* skip = (const float*)d_in[1];
  const float* Wq   = (const float*)d_in[2];
  const float* Kq   = (const float*)d_in[3];
  const float* bq   = (const float*)d_in[4];
  const float* Wk   = (const float*)d_in[5];
  const float* Kk   = (const float*)d_in[6];
  const float* bk   = (const float*)d_in[7];
  const float* Wv   = (const float*)d_in[8];
  const float* Kv   = (const float*)d_in[9];
  const float* bv   = (const float*)d_in[10];
  const float* Wo   = (const float*)d_in[11];
  const float* ng   = (const float*)d_in[12];
  const float* nb   = (const float*)d_in[13];
  const float* c1aw = (const float*)d_in[14];
  const float* c1ab = (const float*)d_in[15];
  const float* c1bw = (const float*)d_in[16];
  const float* c1bb = (const float*)d_in[17];
  const float* c2w  = (const float*)d_in[18];
  const float* c2b  = (const float*)d_in[19];
  const float* w3   = (const float*)d_in[20];
  const float* w4   = (const float*)d_in[21];

  float* out = (float*)d_out;
  float* hp  = out + CFW_;           // h at hp + b*OBS_ + c*FW_

  // ws layout (MiB offsets): bf16 weights 0..16, skip 16, z 20, t 24..36,
  // q 36, k 40, v 44, f32 zf 48, sf 56  (total 64 MiB)
  char* wsb = (char*)d_ws;
  u16* WQb  = (u16*)(wsb);
  u16* WKb  = (u16*)(wsb + ((size_t)4  << 20));
  u16* WVb  = (u16*)(wsb + ((size_t)8  << 20));
  u16* WOb  = (u16*)(wsb + ((size_t)12 << 20));
  u16* skb  = (u16*)(wsb + ((size_t)16 << 20));
  u16* zb16 = (u16*)(wsb + ((size_t)20 << 20));
  u16* tqkv = (u16*)(wsb + ((size_t)24 << 20));
  u16* qbB  = (u16*)(wsb + ((size_t)36 << 20));
  u16* kbB  = (u16*)(wsb + ((size_t)40 << 20));
  u16* vbB  = (u16*)(wsb + ((size_t)44 << 20));
  float* zf = (float*)(wsb + ((size_t)48 << 20));
  float* sf = (float*)(wsb + ((size_t)56 << 20));
  u16* ab   = tqkv;                  // attn out aliases t (t dead then)

  float code = 0.f;
  if (n_in != 22) code += 20000.f;
  if (out_size != 4194304) code += 80000.f;
  if (ws_size < ((size_t)64 << 20)) code += 160000.f;

  dim3 gPix(2, F_, 16);
  dim3 gGemmQKV(8, 4, 48);
  dim3 gGemmWo(8, 4, 16);
  dim3 gLn(8, 8, 2);
  dim3 gAttn(128, 4);
  const int attn_lds_bytes = (512*40 + 32*520 + 8*16*136) * 2;  // 109056

  init_out<<<8192, 256, 0, stream>>>(x, out);
  cvt5<<<dim3(2048, 5), 256, 0, stream>>>(Wq, Wk, Wv, Wo, skip,
                                          WQb, WKb, WVb, WOb, skb);

  auto do_attn = [&](int i, const u16* srcq, const u16* srckv){
    size_t wo16 = (size_t)i*C_*F_*F_;          // per-attn weight offset (u16)
    gemm_qkv_b<<<gGemmQKV, 256, 0, stream>>>(WQb + wo16, WKb + wo16, WVb + wo16,
                                             srcq, srckv, tqkv);
    conv_rope3_b<<<3072, 256, 0, stream>>>(
        tqkv, Kq + i*C_*C_*3, bq + i*C_, Kk + i*C_*C_*3, bk + i*C_,
        Kv + i*C_*C_*3, bv + i*C_, qbB, kbB, vbB);
    attn_mfma_b<<<gAttn, 512, attn_lds_bytes, stream>>>(qbB, kbB, vbB, ab);
    gemm_wo_b<<<gGemmWo, 256, 0, stream>>>(WOb + wo16, ab, hp);
  };

  // z = LN0(x); h = x + att0(z,z) + att1(z,skip)
  ln4_h<<<gLn, 256, 0, stream>>>(x, CFW_, zb16, CFW_, ng + 0*C_*F_, nb + 0*C_*F_);
  do_attn(0, zb16, zb16);
  do_attn(1, zb16, skb);

  // conv block (f32 path)
  ln4_b<<<gLn, 256, 0, stream>>>(hp, OBS_, zf, CFW_, ng + 1*C_*F_, nb + 1*C_*F_);
  dw_fuse_b<<<gPix, 256, 0, stream>>>(zf, CFW_, c1aw, c1ab, c1bw, c1bb, sf, CFW_);
  ln4_b<<<gLn, 256, 0, stream>>>(sf, CFW_, zf, CFW_, ng + 2*C_*F_, nb + 2*C_*F_);
  conv7_add_b<<<gPix, 256, 0, stream>>>(zf, CFW_, c2w, c2b, hp, OBS_);

  // att2 (self on LN3(h))
  ln4_h<<<gLn, 256, 0, stream>>>(hp, OBS_, zb16, CFW_, ng + 3*C_*F_, nb + 3*C_*F_);
  do_attn(2, zb16, zb16);

  // att3 (LN4(h) vs skip)
  ln4_h<<<gLn, 256, 0, stream>>>(hp, OBS_, zb16, CFW_, ng + 4*C_*F_, nb + 4*C_*F_);
  do_attn(3, zb16, skb);

  // FF
  ln4_b<<<gLn, 256, 0, stream>>>(hp, OBS_, zf, CFW_, ng + 5*C_*F_, nb + 5*C_*F_);
  ff_b2<<<gLn, 256, 0, stream>>>(zf, CFW_, w3, w4, hp, OBS_);

  if (code != 0.f) put_val<<<1, 1, 0, stream>>>(out, code);
}

// Round 14
// 438.377 us; speedup vs baseline: 28.9007x; 1.1244x over previous
//
#include <hip/hip_runtime.h>

#define B_ 2
#define C_ 8
#define F_ 256
#define W_ 512
#define H_ 8
#define FW_ (F_*W_)        // 131072
#define CFW_ (C_*FW_)      // 1048576 = one batch of (C,F,W)
#define OBS_ (2*CFW_)      // out batch stride (B,16,F,W)

typedef unsigned short u16;

__device__ __forceinline__ u16 f2bf(float f){
  unsigned u = __float_as_uint(f);
  u += 0x7fffu + ((u>>16)&1u);
  return (u16)(u>>16);
}
__device__ __forceinline__ float bf2f(u16 u){
  return __uint_as_float((unsigned)u<<16);
}

typedef __attribute__((ext_vector_type(8))) short bf16x8;
typedef __attribute__((ext_vector_type(4))) float f32x4;

// ---------------- init: both halves of out = x ----------------
__global__ __launch_bounds__(256)
void init_out(const float* __restrict__ x, float* __restrict__ out){
  int i = blockIdx.x*256 + threadIdx.x;              // 2M
  int b = i >> 20;
  int r = i & (CFW_-1);
  float v = x[i];
  out[(size_t)b*OBS_ + r] = v;
  out[(size_t)b*OBS_ + CFW_ + r] = v;
}

__global__ void put_val(float* o, float v){ o[0] = v; }

// ---------------- bulk f32 -> bf16 conversion (5 arrays of 2,097,152) --------
__global__ __launch_bounds__(256)
void cvt5(const float* __restrict__ s0, const float* __restrict__ s1,
          const float* __restrict__ s2, const float* __restrict__ s3,
          const float* __restrict__ s4,
          u16* __restrict__ d0, u16* __restrict__ d1, u16* __restrict__ d2,
          u16* __restrict__ d3, u16* __restrict__ d4){
  int which = blockIdx.y;
  const float* s = which==0 ? s0 : which==1 ? s1 : which==2 ? s2 : which==3 ? s3 : s4;
  u16* d        = which==0 ? d0 : which==1 ? d1 : which==2 ? d2 : which==3 ? d3 : d4;
  int i = (blockIdx.x*256 + threadIdx.x)*4;          // 2048 blocks x 1024 elems
  float4 v = *(const float4*)(s + i);
  ushort4 o;
  o.x = f2bf(v.x); o.y = f2bf(v.y); o.z = f2bf(v.z); o.w = f2bf(v.w);
  *(ushort4*)(d + i) = o;
}

// ---------------- LayerNorm over f, 32w x 8fs, register-cached ----------------
// grid (16, 8, 2), block 256. BF16OUT selects output type.
template<int BF16OUT>
__global__ __launch_bounds__(256)
void ln32(const float* __restrict__ X, long xbs, void* __restrict__ Yv, long ybs,
          const float* __restrict__ g, const float* __restrict__ bta){
  int wl = threadIdx.x & 31, fs = threadIdx.x >> 5;  // 32 w-lanes x 8 f-slices
  int w = blockIdx.x*32 + wl;
  int c = blockIdx.y;
  int b = blockIdx.z;
  const float* xb = X + (size_t)b*xbs + (size_t)c*FW_ + w;
  float v[32];
  float sum = 0.f, sq = 0.f;
  #pragma unroll
  for (int i = 0; i < 32; ++i){
    v[i] = xb[(size_t)(fs*32 + i)*W_];
    sum += v[i]; sq += v[i]*v[i];
  }
  __shared__ float Ss[8][32], Sq[8][32], Mu[32], Rs[32];
  Ss[fs][wl] = sum; Sq[fs][wl] = sq;
  __syncthreads();
  if (fs == 0){
    float s = 0.f, q = 0.f;
    #pragma unroll
    for (int j = 0; j < 8; ++j){ s += Ss[j][wl]; q += Sq[j][wl]; }
    float mu = s * (1.f/256.f);
    float var = q * (1.f/256.f) - mu*mu;
    Mu[wl] = mu; Rs[wl] = rsqrtf(var + 1e-5f);
  }
  __syncthreads();
  float mu = Mu[wl], rs = Rs[wl];
  if (BF16OUT){
    u16* yb = (u16*)Yv + (size_t)b*ybs + (size_t)c*FW_ + w;
    #pragma unroll
    for (int i = 0; i < 32; ++i){
      int f = fs*32 + i;
      yb[(size_t)f*W_] = f2bf((v[i] - mu)*rs*g[c*F_ + f] + bta[c*F_ + f]);
    }
  } else {
    float* yb = (float*)Yv + (size_t)b*ybs + (size_t)c*FW_ + w;
    #pragma unroll
    for (int i = 0; i < 32; ++i){
      int f = fs*32 + i;
      yb[(size_t)f*W_] = (v[i] - mu)*rs*g[c*F_ + f] + bta[c*F_ + f];
    }
  }
}

// ---------------- fused QKV MFMA GEMM, all-bf16 ----------------
// grid (8 w-tiles, 4 g-tiles(64), 48 = proj*16+b*8+c), block 256.
__global__ __launch_bounds__(256)
void gemm_qkv_b(const u16* __restrict__ wqb, const u16* __restrict__ wkb,
                const u16* __restrict__ wvb,
                const u16* __restrict__ srcq, const u16* __restrict__ srckv,
                u16* __restrict__ T){
  int zid = blockIdx.z;
  int proj = zid >> 4;
  int bc = zid & 15; int b = bc >> 3, c = bc & 7;
  const u16* src = (proj == 0) ? srcq : srckv;
  const u16* Wm  = (proj == 0) ? wqb : (proj == 1 ? wkb : wvb);
  const u16* Ax = src + (size_t)b*CFW_ + (size_t)c*FW_;
  const u16* Bw = Wm + (size_t)c*F_*F_;
  u16* Yb = T + (size_t)proj*2*CFW_ + (size_t)b*CFW_ + (size_t)c*FW_;

  int w0 = blockIdx.x * 64;
  int g0 = blockIdx.y * 64;
  int t = threadIdx.x, lane = t & 63, wv_ = t >> 6;
  int gq = lane >> 4, c16 = lane & 15;
  int wm = w0 + wv_*16 + c16;
  const f32x4 zero4 = {0.f,0.f,0.f,0.f};
  f32x4 acc[4] = {zero4, zero4, zero4, zero4};

  for (int k0 = 0; k0 < F_; k0 += 32){
    union { bf16x8 v8; u16 u[8]; } af;
    #pragma unroll
    for (int j = 0; j < 8; ++j)
      af.u[j] = Ax[(size_t)(k0 + 8*gq + j)*W_ + wm];
    #pragma unroll
    for (int nf = 0; nf < 4; ++nf){
      bf16x8 bfr = *(const bf16x8*)(Bw + (size_t)(g0 + nf*16 + c16)*F_ + k0 + 8*gq);
      acc[nf] = __builtin_amdgcn_mfma_f32_16x16x32_bf16(af.v8, bfr, acc[nf], 0, 0, 0);
    }
  }
  int wout = w0 + wv_*16 + 4*gq;
  #pragma unroll
  for (int nf = 0; nf < 4; ++nf){
    ushort4 o;
    o.x = f2bf(acc[nf][0]); o.y = f2bf(acc[nf][1]);
    o.z = f2bf(acc[nf][2]); o.w = f2bf(acc[nf][3]);
    *(ushort4*)(Yb + (size_t)(g0 + nf*16 + c16)*W_ + wout) = o;
  }
}

// ---------------- Wo MFMA GEMM: h(f32) += a(bf16) @ Wo(bf16) ----------------
// grid (8, 4, 16 = b*8+c), block 256
__global__ __launch_bounds__(256)
void gemm_wo_b(const u16* __restrict__ wob, const u16* __restrict__ A,
               float* __restrict__ Y){
  int bc = blockIdx.z; int b = bc >> 3, c = bc & 7;
  const u16* Ax = A + (size_t)b*CFW_ + (size_t)c*FW_;
  const u16* Bw = wob + (size_t)c*F_*F_;
  float* Yb = Y + (size_t)b*OBS_ + (size_t)c*FW_;
  int w0 = blockIdx.x * 64;
  int g0 = blockIdx.y * 64;
  int t = threadIdx.x, lane = t & 63, wv_ = t >> 6;
  int gq = lane >> 4, c16 = lane & 15;
  int wm = w0 + wv_*16 + c16;
  const f32x4 zero4 = {0.f,0.f,0.f,0.f};
  f32x4 acc[4] = {zero4, zero4, zero4, zero4};

  for (int k0 = 0; k0 < F_; k0 += 32){
    union { bf16x8 v8; u16 u[8]; } af;
    #pragma unroll
    for (int j = 0; j < 8; ++j)
      af.u[j] = Ax[(size_t)(k0 + 8*gq + j)*W_ + wm];
    #pragma unroll
    for (int nf = 0; nf < 4; ++nf){
      bf16x8 bfr = *(const bf16x8*)(Bw + (size_t)(g0 + nf*16 + c16)*F_ + k0 + 8*gq);
      acc[nf] = __builtin_amdgcn_mfma_f32_16x16x32_bf16(af.v8, bfr, acc[nf], 0, 0, 0);
    }
  }
  int wout = w0 + wv_*16 + 4*gq;
  #pragma unroll
  for (int nf = 0; nf < 4; ++nf){
    float* y = Yb + (size_t)(g0 + nf*16 + c16)*W_ + wout;
    float4 o = *(float4*)y;
    o.x += acc[nf][0]; o.y += acc[nf][1]; o.z += acc[nf][2]; o.w += acc[nf][3];
    *(float4*)y = o;
  }
}

// ---------------- fused q/k/v 1x3 conv (+RoPE), LDS-staged, all-co ------------
// grid 768 = p*256 + b*128 + jf, block 256. Block computes all 8 co x 2 f x 512 w.
__global__ __launch_bounds__(256)
void conv_rope_lds(const u16* __restrict__ T,
                   const float* __restrict__ Kq3, const float* __restrict__ bq,
                   const float* __restrict__ Kk3, const float* __restrict__ bk,
                   const float* __restrict__ Kv3, const float* __restrict__ bv,
                   u16* __restrict__ Q, u16* __restrict__ K,
                   u16* __restrict__ V){
  __shared__ float Tin[16][514];                     // zero-padded halo
  __shared__ float Kc[192];                          // [co][ci][tap]
  int bx = blockIdx.x;
  int jf = bx & 127;
  int b  = (bx >> 7) & 1;
  int p  = bx >> 8;                                  // 0..2 (block-uniform)
  const float* K3   = p==0 ? Kq3 : (p==1 ? Kk3 : Kv3);
  const float* bias = p==0 ? bq  : (p==1 ? bk  : bv);
  const u16* Tb = T + (size_t)p*2*CFW_ + (size_t)b*CFW_;
  u16* O = (p==0 ? Q : (p==1 ? K : V)) + (size_t)b*CFW_;
  int f0 = jf*2;
  int t = threadIdx.x;

  if (t < 192) Kc[t] = K3[t];
  if (t < 16){ Tin[t][0] = 0.f; Tin[t][513] = 0.f; }
  for (int li = t; li < 16*128; li += 256){          // 128 ushort4 per row
    int row = li >> 7;                               // ci*2 + fsel
    int c4  = li & 127;
    int ci = row >> 1, fsel = row & 1;
    ushort4 v4 = *(const ushort4*)(Tb + ((size_t)ci*F_ + f0 + fsel)*W_ + c4*4);
    float* dst = &Tin[row][1 + c4*4];
    dst[0] = bf2f(v4.x); dst[1] = bf2f(v4.y);
    dst[2] = bf2f(v4.z); dst[3] = bf2f(v4.w);
  }
  __syncthreads();

  int co = t >> 5;                                   // 0..7
  int wg = t & 31;                                   // 0..31
  int wbase = wg*16;
  float bs = bias[co];
  float a0[16], a1[16];
  #pragma unroll
  for (int i = 0; i < 16; ++i){ a0[i] = bs; a1[i] = bs; }
  #pragma unroll
  for (int ci = 0; ci < 8; ++ci){
    const float* r0 = &Tin[ci*2+0][1 + wbase];
    const float* r1 = &Tin[ci*2+1][1 + wbase];
    float k0 = Kc[(co*8+ci)*3+0], k1 = Kc[(co*8+ci)*3+1], k2 = Kc[(co*8+ci)*3+2];
    #pragma unroll
    for (int i = 0; i < 16; ++i){
      a0[i] += k0*r0[i-1] + k1*r0[i] + k2*r0[i+1];
      a1[i] += k0*r1[i-1] + k1*r1[i] + k2*r1[i+1];
    }
  }
  size_t obase = ((size_t)co*F_ + f0)*W_ + wbase;
  if (p < 2){
    int j = jf & 15;                                 // freq index within head
    float inv = exp2f(-(float)j * 0.83048202372184f);  // 10000^(-j/16)
    float sv, cv, dsn, dcs;
    sincosf((float)wbase * inv, &sv, &cv);
    sincosf(inv, &dsn, &dcs);
    float scale = (p == 0) ? 0.0625f : 1.f;          // fold 1/sqrt(256) into q
    u16 o0[16], o1[16];
    #pragma unroll
    for (int i = 0; i < 16; ++i){
      o0[i] = f2bf((a0[i]*cv - a1[i]*sv)*scale);
      o1[i] = f2bf((a1[i]*cv + a0[i]*sv)*scale);
      float cn = cv*dcs - sv*dsn;                    // rotate by inv
      sv = sv*dcs + cv*dsn;
      cv = cn;
    }
    #pragma unroll
    for (int q4 = 0; q4 < 4; ++q4){
      *(ushort4*)(O + obase + q4*4)      = make_ushort4(o0[q4*4],o0[q4*4+1],o0[q4*4+2],o0[q4*4+3]);
      *(ushort4*)(O + obase + W_ + q4*4) = make_ushort4(o1[q4*4],o1[q4*4+1],o1[q4*4+2],o1[q4*4+3]);
    }
  } else {
    #pragma unroll
    for (int q4 = 0; q4 < 4; ++q4){
      ushort4 p0, p1;
      p0.x = f2bf(a0[q4*4+0]); p0.y = f2bf(a0[q4*4+1]);
      p0.z = f2bf(a0[q4*4+2]); p0.w = f2bf(a0[q4*4+3]);
      p1.x = f2bf(a1[q4*4+0]); p1.y = f2bf(a1[q4*4+1]);
      p1.z = f2bf(a1[q4*4+2]); p1.w = f2bf(a1[q4*4+3]);
      *(ushort4*)(O + obase + q4*4)      = p0;
      *(ushort4*)(O + obase + W_ + q4*4) = p1;
    }
  }
}

// ---------------- MFMA attention, bf16 I/O ----------------
// grid (128 = b*64 + c*8 + h, 4 q-tiles), block 512 (8 waves).
// q is pre-scaled by 1/sqrt(256) at the producer.
__global__ __launch_bounds__(512)
void attn_mfma_b(const u16* __restrict__ q, const u16* __restrict__ k,
                 const u16* __restrict__ v, u16* __restrict__ a){
  extern __shared__ __align__(16) unsigned char smem_dyn[];
  u16* ks = (u16*)smem_dyn;          // [512][40]
  u16* vs = ks + 512*40;             // [32][520]
  u16* ps = vs + 32*520;             // [8][16][136]
  int bx = blockIdx.x;
  int b = bx >> 6;
  int ch = bx & 63;
  int h = ch & 7, c = ch >> 3;
  size_t base = (size_t)b*CFW_ + ((size_t)c*F_ + h*32)*W_;
  int t = threadIdx.x;
  int lane = t & 63, wv = t >> 6;
  int g = lane >> 4, c16 = lane & 15;

  int q0 = blockIdx.y*128 + wv*16;
  union { bf16x8 v8; u16 u[8]; } aq;
  #pragma unroll
  for (int j = 0; j < 8; ++j)
    aq.u[j] = q[base + (size_t)(8*g + j)*W_ + q0 + c16];

  for (int d = 0; d < 32; ++d)
    ks[t*40 + d] = k[base + (size_t)d*W_ + t];       // t = m (512)
  {
    int m8 = (t & 63)*8;
    #pragma unroll
    for (int it = 0; it < 4; ++it){
      int d = (t >> 6) + it*8;
      *(uint4*)(vs + (size_t)d*520 + m8) = *(const uint4*)(v + base + (size_t)d*W_ + m8);
    }
  }
  __syncthreads();

  u16* pw = ps + (size_t)wv*16*136;

  float mrun[4] = {-3e38f,-3e38f,-3e38f,-3e38f};
  float lrun[4] = {0.f,0.f,0.f,0.f};
  const f32x4 zero4 = {0.f,0.f,0.f,0.f};
  f32x4 outacc[2] = {zero4, zero4};

  for (int kt = 0; kt < 4; ++kt){
    f32x4 sv[8];
    #pragma unroll
    for (int mi = 0; mi < 8; ++mi){
      int m0 = kt*128 + mi*16;
      bf16x8 kb8 = *(const bf16x8*)(ks + (size_t)(m0 + c16)*40 + 8*g);
      sv[mi] = __builtin_amdgcn_mfma_f32_16x16x32_bf16(aq.v8, kb8, zero4, 0, 0, 0);
    }
    float pmax[4];
    #pragma unroll
    for (int r = 0; r < 4; ++r){
      float m = sv[0][r];
      #pragma unroll
      for (int mi = 1; mi < 8; ++mi) m = fmaxf(m, sv[mi][r]);
      pmax[r] = m;
    }
    #pragma unroll
    for (int mask = 1; mask <= 8; mask <<= 1){
      #pragma unroll
      for (int r = 0; r < 4; ++r)
        pmax[r] = fmaxf(pmax[r], __shfl_xor(pmax[r], mask));
    }
    float corr[4];
    #pragma unroll
    for (int r = 0; r < 4; ++r){
      float mn = fmaxf(mrun[r], pmax[r]);
      corr[r] = __expf(mrun[r] - mn);
      mrun[r] = mn;
      lrun[r] *= corr[r];
    }
    #pragma unroll
    for (int mi = 0; mi < 8; ++mi){
      #pragma unroll
      for (int r = 0; r < 4; ++r){
        float p = __expf(sv[mi][r] - mrun[r]);
        lrun[r] += p;
        pw[(size_t)(4*g + r)*136 + mi*16 + c16] = f2bf(p);
      }
    }
    f32x4 cv = {corr[0], corr[1], corr[2], corr[3]};
    outacc[0] *= cv;
    outacc[1] *= cv;
    #pragma unroll
    for (int mc = 0; mc < 4; ++mc){
      bf16x8 pa  = *(const bf16x8*)(pw + (size_t)c16*136 + mc*32 + 8*g);
      bf16x8 vb0 = *(const bf16x8*)(vs + (size_t)c16*520      + kt*128 + mc*32 + 8*g);
      bf16x8 vb1 = *(const bf16x8*)(vs + (size_t)(16+c16)*520 + kt*128 + mc*32 + 8*g);
      outacc[0] = __builtin_amdgcn_mfma_f32_16x16x32_bf16(pa, vb0, outacc[0], 0, 0, 0);
      outacc[1] = __builtin_amdgcn_mfma_f32_16x16x32_bf16(pa, vb1, outacc[1], 0, 0, 0);
    }
  }
  float L[4];
  #pragma unroll
  for (int r = 0; r < 4; ++r){
    float s = lrun[r];
    #pragma unroll
    for (int mask = 1; mask <= 8; mask <<= 1) s += __shfl_xor(s, mask);
    L[r] = s;
  }
  #pragma unroll
  for (int dt = 0; dt < 2; ++dt){
    ushort4 o;
    o.x = f2bf(outacc[dt][0] / L[0]);
    o.y = f2bf(outacc[dt][1] / L[1]);
    o.z = f2bf(outacc[dt][2] / L[2]);
    o.w = f2bf(outacc[dt][3] / L[3]);
    *(ushort4*)(a + base + (size_t)(dt*16 + c16)*W_ + q0 + 4*g) = o;
  }
}

// ---------------- depthwise feature convs (f32, batch-strided) ----------------
// grid (2, 256, 16 = b*8+c)
__global__ __launch_bounds__(256)
void dw_fuse_b(const float* __restrict__ Z, long zbs,
               const float* __restrict__ k11, const float* __restrict__ b11,
               const float* __restrict__ k7,  const float* __restrict__ b7,
               float* __restrict__ S, long sbs){
  int w = blockIdx.x*256 + threadIdx.x;
  int f = blockIdx.y;
  int bc = blockIdx.z; int b = bc >> 3, c = bc & 7;
  const float* zb = Z + (size_t)b*zbs + (size_t)c*FW_;
  float a = b11[c];
  #pragma unroll
  for (int i = 0; i < 11; ++i){
    int ff = f - 5 + i;
    if (ff >= 0 && ff < F_) a += k11[c*11 + i]*zb[(size_t)ff*W_ + w];
  }
  float bb = b7[c];
  #pragma unroll
  for (int i = 0; i < 7; ++i){
    int ff = f - 3 + i;
    if (ff >= 0 && ff < F_) bb += k7[c*7 + i]*zb[(size_t)ff*W_ + w];
  }
  float ra = a > 0.f ? a*a : 0.f;
  S[(size_t)b*sbs + ((size_t)c*F_ + f)*W_ + w] = ra + bb;
}

__global__ __launch_bounds__(256)
void conv7_add_b(const float* __restrict__ T, long tbs,
                 const float* __restrict__ k7, const float* __restrict__ b7,
                 float* __restrict__ Hp, long hbs){
  int w = blockIdx.x*256 + threadIdx.x;
  int f = blockIdx.y;
  int bc = blockIdx.z; int b = bc >> 3, c = bc & 7;
  const float* tb = T + (size_t)b*tbs + (size_t)c*FW_;
  float acc = b7[c];
  #pragma unroll
  for (int i = 0; i < 7; ++i){
    int ff = f - 3 + i;
    if (ff >= 0 && ff < F_) acc += k7[c*7 + i]*tb[(size_t)ff*W_ + w];
  }
  Hp[(size_t)b*hbs + ((size_t)c*F_ + f)*W_ + w] += acc;
}

// ---------------- tiny FF: H += w4 @ sq_relu(w3 @ Z) ----------------
// grid (8, 8, 2), block 256
__global__ __launch_bounds__(256)
void ff_b2(const float* __restrict__ Z, long zbs,
           const float* __restrict__ w3, const float* __restrict__ w4,
           float* __restrict__ Hp, long hbs){
  int wl = threadIdx.x & 63, fs = threadIdx.x >> 6;
  int w = blockIdx.x*64 + wl;
  int c = blockIdx.y;
  int b = blockIdx.z;
  const float* zb = Z + (size_t)b*zbs + (size_t)c*FW_ + w;
  float u[4] = {0.f,0.f,0.f,0.f};
  for (int i = 0; i < 64; ++i){
    int f = fs*64 + i;
    float zv = zb[(size_t)f*W_];
    #pragma unroll
    for (int e = 0; e < 4; ++e) u[e] += w3[(c*4 + e)*F_ + f]*zv;
  }
  __shared__ float Us[4][4][64];
  #pragma unroll
  for (int e = 0; e < 4; ++e) Us[fs][e][wl] = u[e];
  __syncthreads();
  float uf[4];
  #pragma unroll
  for (int e = 0; e < 4; ++e){
    float s = Us[0][e][wl] + Us[1][e][wl] + Us[2][e][wl] + Us[3][e][wl];
    float rr = s > 0.f ? s : 0.f;
    uf[e] = rr*rr;
  }
  float* hb = Hp + (size_t)b*hbs + (size_t)c*FW_ + w;
  for (int i = 0; i < 64; ++i){
    int f = fs*64 + i;
    const float* w4r = w4 + (c*F_ + f)*4;
    hb[(size_t)f*W_] += w4r[0]*uf[0] + w4r[1]*uf[1] + w4r[2]*uf[2] + w4r[3]*uf[3];
  }
}

extern "C" void kernel_launch(void* const* d_in, const int* in_sizes, int n_in,
                              void* d_out, int out_size, void* d_ws, size_t ws_size,
                              hipStream_t stream){
  const float* x    = (const float*)d_in[0];
  const float* skip = (const float*)d_in[1];
  const float* Wq   = (const float*)d_in[2];
  const float* Kq   = (const float*)d_in[3];
  const float* bq   = (const float*)d_in[4];
  const float* Wk   = (const float*)d_in[5];
  const float* Kk   = (const float*)d_in[6];
  const float* bk   = (const float*)d_in[7];
  const float* Wv   = (const float*)d_in[8];
  const float* Kv   = (const float*)d_in[9];
  const float* bv   = (const float*)d_in[10];
  const float* Wo   = (const float*)d_in[11];
  const float* ng   = (const float*)d_in[12];
  const float* nb   = (const float*)d_in[13];
  const float* c1aw = (const float*)d_in[14];
  const float* c1ab = (const float*)d_in[15];
  const float* c1bw = (const float*)d_in[16];
  const float* c1bb = (const float*)d_in[17];
  const float* c2w  = (const float*)d_in[18];
  const float* c2b  = (const float*)d_in[19];
  const float* w3   = (const float*)d_in[20];
  const float* w4   = (const float*)d_in[21];

  float* out = (float*)d_out;
  float* hp  = out + CFW_;           // h at hp + b*OBS_ + c*FW_

  // ws layout (MiB offsets): bf16 weights 0..16, skip 16, z 20, t 24..36,
  // q 36, k 40, v 44, f32 zf 48, sf 56  (total 64 MiB)
  char* wsb = (char*)d_ws;
  u16* WQb  = (u16*)(wsb);
  u16* WKb  = (u16*)(wsb + ((size_t)4  << 20));
  u16* WVb  = (u16*)(wsb + ((size_t)8  << 20));
  u16* WOb  = (u16*)(wsb + ((size_t)12 << 20));
  u16* skb  = (u16*)(wsb + ((size_t)16 << 20));
  u16* zb16 = (u16*)(wsb + ((size_t)20 << 20));
  u16* tqkv = (u16*)(wsb + ((size_t)24 << 20));
  u16* qbB  = (u16*)(wsb + ((size_t)36 << 20));
  u16* kbB  = (u16*)(wsb + ((size_t)40 << 20));
  u16* vbB  = (u16*)(wsb + ((size_t)44 << 20));
  float* zf = (float*)(wsb + ((size_t)48 << 20));
  float* sf = (float*)(wsb + ((size_t)56 << 20));
  u16* ab   = tqkv;                  // attn out aliases t (t dead then)

  float code = 0.f;
  if (n_in != 22) code += 20000.f;
  if (out_size != 4194304) code += 80000.f;
  if (ws_size < ((size_t)64 << 20)) code += 160000.f;

  dim3 gPix(2, F_, 16);
  dim3 gGemmQKV(8, 4, 48);
  dim3 gGemmWo(8, 4, 16);
  dim3 gLn(16, 8, 2);
  dim3 gFF(8, 8, 2);
  dim3 gAttn(128, 4);
  const int attn_lds_bytes = (512*40 + 32*520 + 8*16*136) * 2;  // 109056

  init_out<<<8192, 256, 0, stream>>>(x, out);
  cvt5<<<dim3(2048, 5), 256, 0, stream>>>(Wq, Wk, Wv, Wo, skip,
                                          WQb, WKb, WVb, WOb, skb);

  auto do_attn = [&](int i, const u16* srcq, const u16* srckv){
    size_t wo16 = (size_t)i*C_*F_*F_;          // per-attn weight offset (u16)
    gemm_qkv_b<<<gGemmQKV, 256, 0, stream>>>(WQb + wo16, WKb + wo16, WVb + wo16,
                                             srcq, srckv, tqkv);
    conv_rope_lds<<<768, 256, 0, stream>>>(
        tqkv, Kq + i*C_*C_*3, bq + i*C_, Kk + i*C_*C_*3, bk + i*C_,
        Kv + i*C_*C_*3, bv + i*C_, qbB, kbB, vbB);
    attn_mfma_b<<<gAttn, 512, attn_lds_bytes, stream>>>(qbB, kbB, vbB, ab);
    gemm_wo_b<<<gGemmWo, 256, 0, stream>>>(WOb + wo16, ab, hp);
  };

  // z = LN0(x); h = x + att0(z,z) + att1(z,skip)
  ln32<1><<<gLn, 256, 0, stream>>>(x, CFW_, zb16, CFW_, ng + 0*C_*F_, nb + 0*C_*F_);
  do_attn(0, zb16, zb16);
  do_attn(1, zb16, skb);

  // conv block (f32 path)
  ln32<0><<<gLn, 256, 0, stream>>>(hp, OBS_, zf, CFW_, ng + 1*C_*F_, nb + 1*C_*F_);
  dw_fuse_b<<<gPix, 256, 0, stream>>>(zf, CFW_, c1aw, c1ab, c1bw, c1bb, sf, CFW_);
  ln32<0><<<gLn, 256, 0, stream>>>(sf, CFW_, zf, CFW_, ng + 2*C_*F_, nb + 2*C_*F_);
  conv7_add_b<<<gPix, 256, 0, stream>>>(zf, CFW_, c2w, c2b, hp, OBS_);

  // att2 (self on LN3(h))
  ln32<1><<<gLn, 256, 0, stream>>>(hp, OBS_, zb16, CFW_, ng + 3*C_*F_, nb + 3*C_*F_);
  do_attn(2, zb16, zb16);

  // att3 (LN4(h) vs skip)
  ln32<1><<<gLn, 256, 0, stream>>>(hp, OBS_, zb16, CFW_, ng + 4*C_*F_, nb + 4*C_*F_);
  do_attn(3, zb16, skb);

  // FF
  ln32<0><<<gLn, 256, 0, stream>>>(hp, OBS_, zf, CFW_, ng + 5*C_*F_, nb + 5*C_*F_);
  ff_b2<<<gFF, 256, 0, stream>>>(zf, CFW_, w3, w4, hp, OBS_);

  if (code != 0.f) put_val<<<1, 1, 0, stream>>>(out, code);
}